// Round 3
// baseline (116.897 us; speedup 1.0000x reference)
//
#include <hip/hip_runtime.h>

#define EPSD 1e-8
#define FSCD 0.08838834764831845   // python repr(128**-0.5) -> exact same double

// ---------------- lane-permute primitives (32-bit, applied per f64 half) ----
template<int CTRL>
__device__ __forceinline__ int idpp(int x){
  return __builtin_amdgcn_update_dpp(x, x, CTRL, 0xF, 0xF, false);
}
template<int CTRL>
__device__ __forceinline__ double ddpp(double x){
  return __hiloint2double(idpp<CTRL>(__double2hiint(x)),
                          idpp<CTRL>(__double2loint(x)));
}
__device__ __forceinline__ double dxor1(double v){ return ddpp<0xB1>(v); }              // quad_perm [1,0,3,2]
__device__ __forceinline__ double dxor2(double v){ return ddpp<0x4E>(v); }              // quad_perm [2,3,0,1]
__device__ __forceinline__ double dxor4(double v){ return ddpp<0x1B>(ddpp<0x141>(v)); } // xor7(half_mirror) o xor3
__device__ __forceinline__ double dxor8(double v){ return ddpp<0x128>(v); }             // row_ror:8 == xor8
__device__ __forceinline__ void dswap16(double &a, double &b){
  int al=__double2loint(a), ah=__double2hiint(a);
  int bl=__double2loint(b), bh=__double2hiint(b);
  asm("v_permlane16_swap_b32 %0, %1":"+v"(al),"+v"(bl));
  asm("v_permlane16_swap_b32 %0, %1":"+v"(ah),"+v"(bh));
  a=__hiloint2double(ah,al); b=__hiloint2double(bh,bl);
}
// butterfly reductions over the 32-lane row; bitwise lane-uniform result
__device__ __forceinline__ double dredsum(double v){
  v += dxor1(v); v += dxor2(v); v += dxor4(v); v += dxor8(v);
  double a=v, b=v; dswap16(a,b); return a+b;  // {a,b}={v,partner} either orientation
}
__device__ __forceinline__ double dredmax(double v){
  v = fmax(v,dxor1(v)); v = fmax(v,dxor2(v)); v = fmax(v,dxor4(v)); v = fmax(v,dxor8(v));
  double a=v, b=v; dswap16(a,b); return fmax(a,b);
}

// ---------------- 128-pt FWHT, f64; element e = 4*li + j, 32 lanes/row ------
__device__ __forceinline__ void dfwht128(double &v0,double &v1,double &v2,double &v3,
                                         double sg1,double sg2,double sg4,double sg8,double m16){
  double a0=v0+v1, a1=v0-v1, a2=v2+v3, a3=v2-v3;   // strides 1,2 in-register
  v0=a0+a2; v2=a0-a2; v1=a1+a3; v3=a1-a3;
  { double o0=dxor1(v0),o1=dxor1(v1),o2=dxor1(v2),o3=dxor1(v3);   // stride 4
    v0=fma(sg1,v0,o0); v1=fma(sg1,v1,o1); v2=fma(sg1,v2,o2); v3=fma(sg1,v3,o3); }
  { double o0=dxor2(v0),o1=dxor2(v1),o2=dxor2(v2),o3=dxor2(v3);   // stride 8
    v0=fma(sg2,v0,o0); v1=fma(sg2,v1,o1); v2=fma(sg2,v2,o2); v3=fma(sg2,v3,o3); }
  { double o0=dxor4(v0),o1=dxor4(v1),o2=dxor4(v2),o3=dxor4(v3);   // stride 16
    v0=fma(sg4,v0,o0); v1=fma(sg4,v1,o1); v2=fma(sg4,v2,o2); v3=fma(sg4,v3,o3); }
  { double o0=dxor8(v0),o1=dxor8(v1),o2=dxor8(v2),o3=dxor8(v3);   // stride 32
    v0=fma(sg8,v0,o0); v1=fma(sg8,v1,o1); v2=fma(sg8,v2,o2); v3=fma(sg8,v3,o3); }
  { double b,c;                                                    // stride 64
    b=v0;c=v0; dswap16(b,c); v0=fma(m16,v0,b+c);
    b=v1;c=v1; dswap16(b,c); v1=fma(m16,v1,b+c);
    b=v2;c=v2; dswap16(b,c); v2=fma(m16,v2,b+c);
    b=v3;c=v3; dswap16(b,c); v3=fma(m16,v3,b+c); }
}

__global__ __launch_bounds__(256) void tq_kernel(
    const float* __restrict__ x, const float* __restrict__ signs,
    const float* __restrict__ bnd, const float* __restrict__ ctr,
    float* __restrict__ out, int nrowpairs)
{
  __shared__ double Bd[256];   // 255 boundaries + +inf sentinel
  __shared__ float  Cs[256];   // centroids
  const int tid = threadIdx.x;
  if (tid < 255)  Bd[tid] = (double)bnd[tid];
  if (tid == 255) Bd[255] = __builtin_inf();
  Cs[tid] = ctr[tid];
  __syncthreads();

  const int l    = tid & 63;
  const int li   = l & 31;
  const int half = l >> 5;
  const int wid  = tid >> 6;
  const double sg1 = (l & 1) ? -1.0 : 1.0;
  const double sg2 = (l & 2) ? -1.0 : 1.0;
  const double sg4 = (l & 4) ? -1.0 : 1.0;
  const double sg8 = (l & 8) ? -1.0 : 1.0;
  const double m16 = (l & 16) ? -2.0 : 0.0;
  const double max_c = (double)ctr[255];
  const float4 sgf = *reinterpret_cast<const float4*>(signs + 4 * li);
  const double s0 = (double)sgf.x, s1 = (double)sgf.y,
               s2 = (double)sgf.z, s3 = (double)sgf.w;

  // np.searchsorted(boundaries, v, side='left') == #{B[j] < v}; 8-step
  // branchless lower_bound over 256 LDS doubles (Bd[255]=inf pads to pow2).
  auto bsearch = [&](double v) -> int {
    int pos = 0;
    #pragma unroll
    for (int s = 128; s; s >>= 1) pos += (Bd[pos + s - 1] < v) ? s : 0;
    return pos;  // in [0,255]
  };

  for (int t = blockIdx.x * 4 + wid; t < nrowpairs; t += gridDim.x * 4) {
    const int row = 2 * t + half;
    const float4 xv = *reinterpret_cast<const float4*>(x + row * 128 + 4 * li);
    const double x0=(double)xv.x, x1=(double)xv.y, x2=(double)xv.z, x3=(double)xv.w;

    // norms = ||x||_2 (f64) + EPS
    double ss = fma(x0,x0, fma(x1,x1, fma(x2,x2, x3*x3)));
    double norms = sqrt(dredsum(ss)) + EPSD;

    // x_rot = ((x/norms)*signs) @ H * FSC   (true divisions, matching np)
    double r0 = (x0 / norms) * s0;
    double r1 = (x1 / norms) * s1;
    double r2 = (x2 / norms) * s2;
    double r3 = (x3 / norms) * s3;
    dfwht128(r0, r1, r2, r3, sg1, sg2, sg4, sg8, m16);
    r0 *= FSCD; r1 *= FSCD; r2 *= FSCD; r3 *= FSCD;

    // stats
    double ab0=fabs(r0), ab1=fabs(r1), ab2=fabs(r2), ab3=fabs(r3);
    double xmax  = dredmax(fmax(fmax(ab0,ab1), fmax(ab2,ab3)));
    double xmean = dredsum((ab0+ab1)+(ab2+ab3)) / 128.0 + EPSD;
    double rms   = xmax / max_c;
    bool   spiky = (xmax / xmean) > 5.0;

    // pass 1: idx_tmp = searchsorted(B, x_rot/(rms+EPS))
    double d1 = rms + EPSD;
    int  i0 = bsearch(r0 / d1), i1 = bsearch(r1 / d1),
         i2 = bsearch(r2 / d1), i3 = bsearch(r3 / d1);
    double c10=(double)Cs[i0], c11=(double)Cs[i1],
           c12=(double)Cs[i2], c13=(double)Cs[i3];

    // gamma refine
    double num = dredsum(fma(r0,c10, fma(r1,c11, fma(r2,c12, r3*c13))));
    double den = dredsum(fma(c10,c10, fma(c11,c11, fma(c12,c12, c13*c13)))) + EPSD;
    double gamma1 = num / den;

    // pass 2
    double d2 = gamma1 + EPSD;
    int  j0 = bsearch(r0 / d2), j1 = bsearch(r1 / d2),
         j2 = bsearch(r2 / d2), j3 = bsearch(r3 / d2);
    double c20=(double)Cs[j0], c21=(double)Cs[j1],
           c22=(double)Cs[j2], c23=(double)Cs[j3];

    // select, reconstruct: recon = c[idx]*gamma ; then *FSC, inv-FWHT, *signs, *norms
    double gamma = spiky ? rms : gamma1;
    double y0 = ((spiky ? c10 : c20) * gamma) * FSCD;
    double y1 = ((spiky ? c11 : c21) * gamma) * FSCD;
    double y2 = ((spiky ? c12 : c22) * gamma) * FSCD;
    double y3 = ((spiky ? c13 : c23) * gamma) * FSCD;
    dfwht128(y0, y1, y2, y3, sg1, sg2, sg4, sg8, m16);

    float4 ov;
    ov.x = (float)(y0 * s0 * norms);
    ov.y = (float)(y1 * s1 * norms);
    ov.z = (float)(y2 * s2 * norms);
    ov.w = (float)(y3 * s3 * norms);
    *reinterpret_cast<float4*>(out + row * 128 + 4 * li) = ov;
  }
}

extern "C" void kernel_launch(void* const* d_in, const int* in_sizes, int n_in,
                              void* d_out, int out_size, void* d_ws, size_t ws_size,
                              hipStream_t stream) {
  const float* x     = (const float*)d_in[0];
  const float* signs = (const float*)d_in[1];
  // d_in[2] = wht (unused: Sylvester Hadamard applied as in-register FWHT)
  const float* bnd   = (const float*)d_in[3];
  const float* ctr   = (const float*)d_in[4];
  float* out = (float*)d_out;

  int nrows     = out_size / 128;
  int nrowpairs = nrows / 2;                 // 2 rows per wave
  int blocks = (nrowpairs + 3) / 4;          // 4 waves per block
  if (blocks > 2048) blocks = 2048;
  hipLaunchKernelGGL(tq_kernel, dim3(blocks), dim3(256), 0, stream,
                     x, signs, bnd, ctr, out, nrowpairs);
}

// Round 4
// 91.575 us; speedup vs baseline: 1.2765x; 1.2765x over previous
//
#include <hip/hip_runtime.h>

#define NCELL 1024
#define EPSD  1e-8
#define FSCD  0.08838834764831845    // 128**-0.5 (exact double of python repr)
#define FSCF  0.08838834764831845f

// ---------------- lane-permute primitives ----------------
template<int CTRL>
__device__ __forceinline__ int idpp(int x){
  return __builtin_amdgcn_update_dpp(x, x, CTRL, 0xF, 0xF, false);
}
template<int CTRL>
__device__ __forceinline__ float fdpp(float x){
  return __int_as_float(idpp<CTRL>(__float_as_int(x)));
}
// f32
__device__ __forceinline__ float xorl1(float v){ return fdpp<0xB1>(v); }              // quad_perm [1,0,3,2]
__device__ __forceinline__ float xorl2(float v){ return fdpp<0x4E>(v); }              // quad_perm [2,3,0,1]
__device__ __forceinline__ float xorl4(float v){ return fdpp<0x1B>(fdpp<0x141>(v)); } // xor7(half_mirror) o xor3
__device__ __forceinline__ float xorl8(float v){ return fdpp<0x128>(v); }             // row_ror:8 == xor8
__device__ __forceinline__ void swap16(float &a, float &b){
  asm("v_permlane16_swap_b32 %0, %1" : "+v"(a), "+v"(b));
}
// f64 (per-half DPP)
template<int CTRL>
__device__ __forceinline__ double ddpp(double x){
  return __hiloint2double(idpp<CTRL>(__double2hiint(x)),
                          idpp<CTRL>(__double2loint(x)));
}
__device__ __forceinline__ double dxor1(double v){ return ddpp<0xB1>(v); }
__device__ __forceinline__ double dxor2(double v){ return ddpp<0x4E>(v); }
__device__ __forceinline__ double dxor4(double v){ return ddpp<0x1B>(ddpp<0x141>(v)); }
__device__ __forceinline__ double dxor8(double v){ return ddpp<0x128>(v); }
__device__ __forceinline__ void dswap16(double &a, double &b){
  int al=__double2loint(a), ah=__double2hiint(a);
  int bl=__double2loint(b), bh=__double2hiint(b);
  asm("v_permlane16_swap_b32 %0, %1":"+v"(al),"+v"(bl));
  asm("v_permlane16_swap_b32 %0, %1":"+v"(ah),"+v"(bh));
  a=__hiloint2double(ah,al); b=__hiloint2double(bh,bl);
}
// butterfly reductions over the 32-lane row (bitwise lane-uniform)
__device__ __forceinline__ double dredsum(double v){
  v += dxor1(v); v += dxor2(v); v += dxor4(v); v += dxor8(v);
  double a=v, b=v; dswap16(a,b); return a+b;  // {a,b}={v,partner} either orientation
}
__device__ __forceinline__ double dredmax(double v){
  v = fmax(v,dxor1(v)); v = fmax(v,dxor2(v)); v = fmax(v,dxor4(v)); v = fmax(v,dxor8(v));
  double a=v, b=v; dswap16(a,b); return fmax(a,b);
}

// ---------------- 128-pt FWHT, f64 (forward / decision path) ----------------
__device__ __forceinline__ void dfwht128(double &v0,double &v1,double &v2,double &v3,
                                         double sg1,double sg2,double sg4,double sg8,double m16){
  double a0=v0+v1, a1=v0-v1, a2=v2+v3, a3=v2-v3;   // strides 1,2 in-register
  v0=a0+a2; v2=a0-a2; v1=a1+a3; v3=a1-a3;
  { double o0=dxor1(v0),o1=dxor1(v1),o2=dxor1(v2),o3=dxor1(v3);   // stride 4
    v0=fma(sg1,v0,o0); v1=fma(sg1,v1,o1); v2=fma(sg1,v2,o2); v3=fma(sg1,v3,o3); }
  { double o0=dxor2(v0),o1=dxor2(v1),o2=dxor2(v2),o3=dxor2(v3);   // stride 8
    v0=fma(sg2,v0,o0); v1=fma(sg2,v1,o1); v2=fma(sg2,v2,o2); v3=fma(sg2,v3,o3); }
  { double o0=dxor4(v0),o1=dxor4(v1),o2=dxor4(v2),o3=dxor4(v3);   // stride 16
    v0=fma(sg4,v0,o0); v1=fma(sg4,v1,o1); v2=fma(sg4,v2,o2); v3=fma(sg4,v3,o3); }
  { double o0=dxor8(v0),o1=dxor8(v1),o2=dxor8(v2),o3=dxor8(v3);   // stride 32
    v0=fma(sg8,v0,o0); v1=fma(sg8,v1,o1); v2=fma(sg8,v2,o2); v3=fma(sg8,v3,o3); }
  { double b,c;                                                    // stride 64
    b=v0;c=v0; dswap16(b,c); v0=fma(m16,v0,b+c);
    b=v1;c=v1; dswap16(b,c); v1=fma(m16,v1,b+c);
    b=v2;c=v2; dswap16(b,c); v2=fma(m16,v2,b+c);
    b=v3;c=v3; dswap16(b,c); v3=fma(m16,v3,b+c); }
}

// ---------------- 128-pt FWHT, f32 (inverse path: linear, no decisions) -----
__device__ __forceinline__ void fwht128f(float &v0,float &v1,float &v2,float &v3,
                                         float sg1,float sg2,float sg4,float sg8,float m16){
  float a0=v0+v1, a1=v0-v1, a2=v2+v3, a3=v2-v3;
  v0=a0+a2; v2=a0-a2; v1=a1+a3; v3=a1-a3;
  { float o0=xorl1(v0),o1=xorl1(v1),o2=xorl1(v2),o3=xorl1(v3);
    v0=fmaf(sg1,v0,o0); v1=fmaf(sg1,v1,o1); v2=fmaf(sg1,v2,o2); v3=fmaf(sg1,v3,o3); }
  { float o0=xorl2(v0),o1=xorl2(v1),o2=xorl2(v2),o3=xorl2(v3);
    v0=fmaf(sg2,v0,o0); v1=fmaf(sg2,v1,o1); v2=fmaf(sg2,v2,o2); v3=fmaf(sg2,v3,o3); }
  { float o0=xorl4(v0),o1=xorl4(v1),o2=xorl4(v2),o3=xorl4(v3);
    v0=fmaf(sg4,v0,o0); v1=fmaf(sg4,v1,o1); v2=fmaf(sg4,v2,o2); v3=fmaf(sg4,v3,o3); }
  { float o0=xorl8(v0),o1=xorl8(v1),o2=xorl8(v2),o3=xorl8(v3);
    v0=fmaf(sg8,v0,o0); v1=fmaf(sg8,v1,o1); v2=fmaf(sg8,v2,o2); v3=fmaf(sg8,v3,o3); }
  { float b,c;
    b=v0;c=v0; swap16(b,c); v0=fmaf(m16,v0,b+c);
    b=v1;c=v1; swap16(b,c); v1=fmaf(m16,v1,b+c);
    b=v2;c=v2; swap16(b,c); v2=fmaf(m16,v2,b+c);
    b=v3;c=v3; swap16(b,c); v3=fmaf(m16,v3,b+c); }
}

__global__ __launch_bounds__(256) void tq_kernel(
    const float* __restrict__ x, const float* __restrict__ signs,
    const float* __restrict__ bnd, const float* __restrict__ ctr,
    float* __restrict__ out, int nrowpairs)
{
  // searchsorted LUT with exact-f64 semantics:
  //   cell ic = clamp((v-lo)*scale); entry {bm1=Bd[pos-1], b0=Bd[pos], pos}
  //   idx = pos-1 + (bm1<v) + (b0<v)
  // Correct under +/-1 cell misassignment because cell width (7.7/1024=0.0075)
  // < min Lloyd-Max boundary gap (~0.017) -> <=1 boundary per cell(+eps).
  __shared__ double2 lutB[NCELL];   // 16 KB
  __shared__ int     lutP[NCELL];   //  4 KB
  __shared__ double  Bd[256];       //  2 KB (255 boundaries + +inf sentinel)
  __shared__ float   Cs[256];       //  1 KB centroids
  const int tid = threadIdx.x;
  if (tid < 255)  Bd[tid] = (double)bnd[tid];
  if (tid == 255) Bd[255] = __builtin_inf();
  Cs[tid] = ctr[tid];
  __syncthreads();

  const double lo    = Bd[0] - 0.01;
  const double cw    = (Bd[254] + 0.01 - lo) * (1.0 / NCELL);
  const double scale = 1.0 / cw;

  for (int c = tid; c < NCELL; c += 256) {
    double cl = fma((double)c, cw, lo);
    int pos = 0;
    #pragma unroll
    for (int s = 128; s; s >>= 1) pos += (Bd[pos + s - 1] < cl) ? s : 0;
    lutB[c] = make_double2((pos == 0) ? -__builtin_inf() : Bd[pos - 1], Bd[pos]);
    lutP[c] = pos;
  }
  __syncthreads();

  const int l    = tid & 63;
  const int li   = l & 31;
  const int half = l >> 5;
  const int wid  = tid >> 6;
  const double sg1 = (l & 1) ? -1.0 : 1.0;
  const double sg2 = (l & 2) ? -1.0 : 1.0;
  const double sg4 = (l & 4) ? -1.0 : 1.0;
  const double sg8 = (l & 8) ? -1.0 : 1.0;
  const double m16 = (l & 16) ? -2.0 : 0.0;
  const float  sg1f = (l & 1) ? -1.f : 1.f;
  const float  sg2f = (l & 2) ? -1.f : 1.f;
  const float  sg4f = (l & 4) ? -1.f : 1.f;
  const float  sg8f = (l & 8) ? -1.f : 1.f;
  const float  m16f = (l & 16) ? -2.f : 0.f;
  const double max_c = (double)ctr[255];
  const float4 sgf = *reinterpret_cast<const float4*>(signs + 4 * li);
  const double s0 = (double)sgf.x, s1 = (double)sgf.y,
               s2 = (double)sgf.z, s3 = (double)sgf.w;

  auto qsearch = [&](double v) -> int {
    double cf = (v - lo) * scale;
    cf = fmin(fmax(cf, 0.0), (double)(NCELL - 1));
    int ic = (int)cf;
    double2 bb = lutB[ic];
    return lutP[ic] - 1 + ((bb.x < v) ? 1 : 0) + ((bb.y < v) ? 1 : 0);
  };

  for (int t = blockIdx.x * 4 + wid; t < nrowpairs; t += gridDim.x * 4) {
    const int row = 2 * t + half;
    const float4 xv = *reinterpret_cast<const float4*>(x + row * 128 + 4 * li);
    const double x0=(double)xv.x, x1=(double)xv.y, x2=(double)xv.z, x3=(double)xv.w;

    // norms = ||x||_2 (f64) + EPS
    double ss = fma(x0,x0, fma(x1,x1, fma(x2,x2, x3*x3)));
    double norms = sqrt(dredsum(ss)) + EPSD;

    // x_rot = ((x/norms)*signs) @ H * FSC   (identical op order to R3)
    double r0 = (x0 / norms) * s0;
    double r1 = (x1 / norms) * s1;
    double r2 = (x2 / norms) * s2;
    double r3 = (x3 / norms) * s3;
    dfwht128(r0, r1, r2, r3, sg1, sg2, sg4, sg8, m16);
    r0 *= FSCD; r1 *= FSCD; r2 *= FSCD; r3 *= FSCD;

    // stats
    double ab0=fabs(r0), ab1=fabs(r1), ab2=fabs(r2), ab3=fabs(r3);
    double xmax  = dredmax(fmax(fmax(ab0,ab1), fmax(ab2,ab3)));
    double xmean = dredsum((ab0+ab1)+(ab2+ab3)) / 128.0 + EPSD;
    double rms   = xmax / max_c;
    bool   spiky = (xmax / xmean) > 5.0;

    // pass 1
    double d1 = rms + EPSD;
    int  i0 = qsearch(r0 / d1), i1 = qsearch(r1 / d1),
         i2 = qsearch(r2 / d1), i3 = qsearch(r3 / d1);
    float c10f=Cs[i0], c11f=Cs[i1], c12f=Cs[i2], c13f=Cs[i3];
    double c10=(double)c10f, c11=(double)c11f, c12=(double)c12f, c13=(double)c13f;

    // gamma refine (f64, identical to R3)
    double num = dredsum(fma(r0,c10, fma(r1,c11, fma(r2,c12, r3*c13))));
    double den = dredsum(fma(c10,c10, fma(c11,c11, fma(c12,c12, c13*c13)))) + EPSD;
    double gamma1 = num / den;

    // pass 2
    double d2 = gamma1 + EPSD;
    int  j0 = qsearch(r0 / d2), j1 = qsearch(r1 / d2),
         j2 = qsearch(r2 / d2), j3 = qsearch(r3 / d2);
    float c20f=Cs[j0], c21f=Cs[j1], c22f=Cs[j2], c23f=Cs[j3];

    // reconstruct + inverse rotation in f32 (linear path, no decisions)
    double gamma = spiky ? rms : gamma1;
    float g2f = (float)(gamma * FSCD);
    float y0 = (spiky ? c10f : c20f) * g2f;
    float y1 = (spiky ? c11f : c21f) * g2f;
    float y2 = (spiky ? c12f : c22f) * g2f;
    float y3 = (spiky ? c13f : c23f) * g2f;
    fwht128f(y0, y1, y2, y3, sg1f, sg2f, sg4f, sg8f, m16f);

    const float nf = (float)norms;
    float4 ov;
    ov.x = y0 * sgf.x * nf;
    ov.y = y1 * sgf.y * nf;
    ov.z = y2 * sgf.z * nf;
    ov.w = y3 * sgf.w * nf;
    *reinterpret_cast<float4*>(out + row * 128 + 4 * li) = ov;
  }
}

extern "C" void kernel_launch(void* const* d_in, const int* in_sizes, int n_in,
                              void* d_out, int out_size, void* d_ws, size_t ws_size,
                              hipStream_t stream) {
  const float* x     = (const float*)d_in[0];
  const float* signs = (const float*)d_in[1];
  // d_in[2] = wht (unused: Sylvester Hadamard applied as in-register FWHT)
  const float* bnd   = (const float*)d_in[3];
  const float* ctr   = (const float*)d_in[4];
  float* out = (float*)d_out;

  int nrows     = out_size / 128;
  int nrowpairs = nrows / 2;                 // 2 rows per wave
  int blocks = (nrowpairs + 3) / 4;          // 4 waves per block
  if (blocks > 2048) blocks = 2048;
  hipLaunchKernelGGL(tq_kernel, dim3(blocks), dim3(256), 0, stream,
                     x, signs, bnd, ctr, out, nrowpairs);
}

// Round 5
// 78.238 us; speedup vs baseline: 1.4941x; 1.1705x over previous
//
#include <hip/hip_runtime.h>

#define NCELL 1024
#define EPSD  1e-8
#define FSCD  0.08838834764831845    // 128**-0.5 (exact double of python repr)

// ---------------- lane-permute primitives ----------------
template<int CTRL>
__device__ __forceinline__ int idpp(int x){
  return __builtin_amdgcn_update_dpp(x, x, CTRL, 0xF, 0xF, false);
}
template<int CTRL>
__device__ __forceinline__ float fdpp(float x){
  return __int_as_float(idpp<CTRL>(__float_as_int(x)));
}
// f32
__device__ __forceinline__ float xorl1(float v){ return fdpp<0xB1>(v); }              // quad_perm [1,0,3,2]
__device__ __forceinline__ float xorl2(float v){ return fdpp<0x4E>(v); }              // quad_perm [2,3,0,1]
__device__ __forceinline__ float xorl4(float v){ return fdpp<0x1B>(fdpp<0x141>(v)); } // xor7(half_mirror) o xor3
__device__ __forceinline__ float xorl8(float v){ return fdpp<0x128>(v); }             // row_ror:8 == xor8
__device__ __forceinline__ void swap16(float &a, float &b){
  asm("v_permlane16_swap_b32 %0, %1" : "+v"(a), "+v"(b));
}
// f64 (per-half DPP)
template<int CTRL>
__device__ __forceinline__ double ddpp(double x){
  return __hiloint2double(idpp<CTRL>(__double2hiint(x)),
                          idpp<CTRL>(__double2loint(x)));
}
__device__ __forceinline__ double dxor1(double v){ return ddpp<0xB1>(v); }
__device__ __forceinline__ double dxor2(double v){ return ddpp<0x4E>(v); }
__device__ __forceinline__ double dxor4(double v){ return ddpp<0x1B>(ddpp<0x141>(v)); }
__device__ __forceinline__ double dxor8(double v){ return ddpp<0x128>(v); }
__device__ __forceinline__ void dswap16(double &a, double &b){
  int al=__double2loint(a), ah=__double2hiint(a);
  int bl=__double2loint(b), bh=__double2hiint(b);
  asm("v_permlane16_swap_b32 %0, %1":"+v"(al),"+v"(bl));
  asm("v_permlane16_swap_b32 %0, %1":"+v"(ah),"+v"(bh));
  a=__hiloint2double(ah,al); b=__hiloint2double(bh,bl);
}
// butterfly reductions over the 32-lane row (bitwise lane-uniform)
__device__ __forceinline__ double dredsum(double v){
  v += dxor1(v); v += dxor2(v); v += dxor4(v); v += dxor8(v);
  double a=v, b=v; dswap16(a,b); return a+b;  // {a,b}={v,partner} either orientation
}
__device__ __forceinline__ double dredmax(double v){
  v = fmax(v,dxor1(v)); v = fmax(v,dxor2(v)); v = fmax(v,dxor4(v)); v = fmax(v,dxor8(v));
  double a=v, b=v; dswap16(a,b); return fmax(a,b);
}

// ---------------- 128-pt FWHT, f64 (forward / decision path) ----------------
__device__ __forceinline__ void dfwht128(double &v0,double &v1,double &v2,double &v3,
                                         double sg1,double sg2,double sg4,double sg8,double m16){
  double a0=v0+v1, a1=v0-v1, a2=v2+v3, a3=v2-v3;   // strides 1,2 in-register
  v0=a0+a2; v2=a0-a2; v1=a1+a3; v3=a1-a3;
  { double o0=dxor1(v0),o1=dxor1(v1),o2=dxor1(v2),o3=dxor1(v3);   // stride 4
    v0=fma(sg1,v0,o0); v1=fma(sg1,v1,o1); v2=fma(sg1,v2,o2); v3=fma(sg1,v3,o3); }
  { double o0=dxor2(v0),o1=dxor2(v1),o2=dxor2(v2),o3=dxor2(v3);   // stride 8
    v0=fma(sg2,v0,o0); v1=fma(sg2,v1,o1); v2=fma(sg2,v2,o2); v3=fma(sg2,v3,o3); }
  { double o0=dxor4(v0),o1=dxor4(v1),o2=dxor4(v2),o3=dxor4(v3);   // stride 16
    v0=fma(sg4,v0,o0); v1=fma(sg4,v1,o1); v2=fma(sg4,v2,o2); v3=fma(sg4,v3,o3); }
  { double o0=dxor8(v0),o1=dxor8(v1),o2=dxor8(v2),o3=dxor8(v3);   // stride 32
    v0=fma(sg8,v0,o0); v1=fma(sg8,v1,o1); v2=fma(sg8,v2,o2); v3=fma(sg8,v3,o3); }
  { double b,c;                                                    // stride 64
    b=v0;c=v0; dswap16(b,c); v0=fma(m16,v0,b+c);
    b=v1;c=v1; dswap16(b,c); v1=fma(m16,v1,b+c);
    b=v2;c=v2; dswap16(b,c); v2=fma(m16,v2,b+c);
    b=v3;c=v3; dswap16(b,c); v3=fma(m16,v3,b+c); }
}

// ---------------- 128-pt FWHT, f32 (inverse path: linear, no decisions) -----
__device__ __forceinline__ void fwht128f(float &v0,float &v1,float &v2,float &v3,
                                         float sg1,float sg2,float sg4,float sg8,float m16){
  float a0=v0+v1, a1=v0-v1, a2=v2+v3, a3=v2-v3;
  v0=a0+a2; v2=a0-a2; v1=a1+a3; v3=a1-a3;
  { float o0=xorl1(v0),o1=xorl1(v1),o2=xorl1(v2),o3=xorl1(v3);
    v0=fmaf(sg1,v0,o0); v1=fmaf(sg1,v1,o1); v2=fmaf(sg1,v2,o2); v3=fmaf(sg1,v3,o3); }
  { float o0=xorl2(v0),o1=xorl2(v1),o2=xorl2(v2),o3=xorl2(v3);
    v0=fmaf(sg2,v0,o0); v1=fmaf(sg2,v1,o1); v2=fmaf(sg2,v2,o2); v3=fmaf(sg2,v3,o3); }
  { float o0=xorl4(v0),o1=xorl4(v1),o2=xorl4(v2),o3=xorl4(v3);
    v0=fmaf(sg4,v0,o0); v1=fmaf(sg4,v1,o1); v2=fmaf(sg4,v2,o2); v3=fmaf(sg4,v3,o3); }
  { float o0=xorl8(v0),o1=xorl8(v1),o2=xorl8(v2),o3=xorl8(v3);
    v0=fmaf(sg8,v0,o0); v1=fmaf(sg8,v1,o1); v2=fmaf(sg8,v2,o2); v3=fmaf(sg8,v3,o3); }
  { float b,c;
    b=v0;c=v0; swap16(b,c); v0=fmaf(m16,v0,b+c);
    b=v1;c=v1; swap16(b,c); v1=fmaf(m16,v1,b+c);
    b=v2;c=v2; swap16(b,c); v2=fmaf(m16,v2,b+c);
    b=v3;c=v3; swap16(b,c); v3=fmaf(m16,v3,b+c); }
}

__global__ __launch_bounds__(256) void tq_kernel(
    const float* __restrict__ x, const float* __restrict__ signs,
    const float* __restrict__ bnd, const float* __restrict__ ctr,
    float* __restrict__ out, int nrowpairs)
{
  // searchsorted LUT, f64-exact semantics:
  //   cell ic = clamp((v-lo)*scale); entry {bm1=Bd[pos-1], b0=Bd[pos], pos}
  //   idx = pos-1 + (bm1<v) + (b0<v)
  // Tolerates +/-1-cell or +/-1-pos slop because cell width (0.0075) satisfies
  // 2*cw < min Lloyd-Max boundary gap (~0.0166).
  __shared__ double2 lutB[NCELL];   // 16 KB
  __shared__ int     lutP[NCELL];   //  4 KB
  __shared__ double  Bd[256];       //  2 KB (255 boundaries + +inf sentinel)
  __shared__ float   Cs[256];       //  1 KB centroids
  const int tid = threadIdx.x;
  if (tid < 255)  Bd[tid] = (double)bnd[tid];
  if (tid == 255) Bd[255] = __builtin_inf();
  Cs[tid] = ctr[tid];
  __syncthreads();

  const double lo    = Bd[0] - 0.01;
  const double cw    = (Bd[254] + 0.01 - lo) * (1.0 / NCELL);
  const double scale = 1.0 / cw;
  const double nls   = -lo * scale;

  // O(1)-depth LUT build: thread i owns pos=i, writes its contiguous cell range.
  // c_start(i) = floor((Bd[i-1]-lo)*scale)+1 -> exact partition of [0,NCELL).
  {
    const int i = tid;
    double bm1 = (i == 0) ? -__builtin_inf() : Bd[i - 1];
    double b0  = Bd[i];
    int cs = (i == 0)   ? 0     : (int)floor((Bd[i - 1] - lo) * scale) + 1;
    int ce = (i == 255) ? NCELL : (int)floor((Bd[i]     - lo) * scale) + 1;
    cs = max(cs, 0); ce = min(ce, NCELL);
    for (int c = cs; c < ce; ++c) {
      lutB[c] = make_double2(bm1, b0);
      lutP[c] = i;
    }
  }
  __syncthreads();

  const int l    = tid & 63;
  const int li   = l & 31;
  const int half = l >> 5;
  const int wid  = tid >> 6;
  const double sg1 = (l & 1) ? -1.0 : 1.0;
  const double sg2 = (l & 2) ? -1.0 : 1.0;
  const double sg4 = (l & 4) ? -1.0 : 1.0;
  const double sg8 = (l & 8) ? -1.0 : 1.0;
  const double m16 = (l & 16) ? -2.0 : 0.0;
  const float  sg1f = (l & 1) ? -1.f : 1.f;
  const float  sg2f = (l & 2) ? -1.f : 1.f;
  const float  sg4f = (l & 4) ? -1.f : 1.f;
  const float  sg8f = (l & 8) ? -1.f : 1.f;
  const float  m16f = (l & 16) ? -2.f : 0.f;
  const double inv_maxc = 1.0 / (double)ctr[255];
  const float4 sgf = *reinterpret_cast<const float4*>(signs + 4 * li);

  // search with folded scale: v = rr*kd ; cell = fma(rr, kd*scale, nls)
  auto qsearch = [&](double rr, double A, double kd) -> int {
    double cf = fma(rr, A, nls);
    cf = fmin(fmax(cf, 0.0), (double)(NCELL - 1));
    int ic = (int)cf;
    double v = rr * kd;
    double2 bb = lutB[ic];
    return lutP[ic] - 1 + ((bb.x < v) ? 1 : 0) + ((bb.y < v) ? 1 : 0);
  };

  for (int t = blockIdx.x * 4 + wid; t < nrowpairs; t += gridDim.x * 4) {
    const int row = 2 * t + half;
    const float4 xv = *reinterpret_cast<const float4*>(x + row * 128 + 4 * li);

    // sign fold exact in f32, widen; rr = unnormalized FWHT(x*s)
    double rr0 = (double)(xv.x * sgf.x);
    double rr1 = (double)(xv.y * sgf.y);
    double rr2 = (double)(xv.z * sgf.z);
    double rr3 = (double)(xv.w * sgf.w);

    // norms = ||x||_2 (f64) + EPS  ((x*s)^2 == x^2 exactly)
    double ss = fma(rr0,rr0, fma(rr1,rr1, fma(rr2,rr2, rr3*rr3)));
    double norms = sqrt(dredsum(ss)) + EPSD;

    dfwht128(rr0, rr1, rr2, rr3, sg1, sg2, sg4, sg8, m16);
    const double k = FSCD / norms;        // x_rot = rr * k   (div #1)

    // stats on rr, scaled by k once
    double ab0=fabs(rr0), ab1=fabs(rr1), ab2=fabs(rr2), ab3=fabs(rr3);
    double xmax  = dredmax(fmax(fmax(ab0,ab1), fmax(ab2,ab3))) * k;
    double asum  = dredsum((ab0+ab1)+(ab2+ab3));
    double xmean = fma(asum * 0.0078125, k, EPSD);
    bool   spiky = xmax > 5.0 * xmean;
    double rms   = xmax * inv_maxc;

    // pass 1: searchsorted(B, x_rot/(rms+EPS)) via v = rr*(k/(rms+EPS))
    double invd1 = 1.0 / (rms + EPSD);    // div #2
    double kd1 = k * invd1, A1 = kd1 * scale;
    int  i0 = qsearch(rr0, A1, kd1), i1 = qsearch(rr1, A1, kd1),
         i2 = qsearch(rr2, A1, kd1), i3 = qsearch(rr3, A1, kd1);
    float c10f=Cs[i0], c11f=Cs[i1], c12f=Cs[i2], c13f=Cs[i3];
    double c10=(double)c10f, c11=(double)c11f, c12=(double)c12f, c13=(double)c13f;

    // gamma refine: num = k * <rr, c>;  den = <c, c> + EPS
    double num = dredsum(fma(rr0,c10, fma(rr1,c11, fma(rr2,c12, rr3*c13)))) * k;
    double den = dredsum(fma(c10,c10, fma(c11,c11, fma(c12,c12, c13*c13)))) + EPSD;
    double gamma1 = num / den;            // div #3

    // pass 2
    double invd2 = 1.0 / (gamma1 + EPSD); // div #4
    double kd2 = k * invd2, A2 = kd2 * scale;
    int  j0 = qsearch(rr0, A2, kd2), j1 = qsearch(rr1, A2, kd2),
         j2 = qsearch(rr2, A2, kd2), j3 = qsearch(rr3, A2, kd2);
    float c20f=Cs[j0], c21f=Cs[j1], c22f=Cs[j2], c23f=Cs[j3];

    // reconstruct + inverse rotation in f32 (linear path, no decisions)
    double gamma = spiky ? rms : gamma1;
    float g2f = (float)(gamma * FSCD);
    float y0 = (spiky ? c10f : c20f) * g2f;
    float y1 = (spiky ? c11f : c21f) * g2f;
    float y2 = (spiky ? c12f : c22f) * g2f;
    float y3 = (spiky ? c13f : c23f) * g2f;
    fwht128f(y0, y1, y2, y3, sg1f, sg2f, sg4f, sg8f, m16f);

    const float nf = (float)norms;
    float4 ov;
    ov.x = y0 * sgf.x * nf;
    ov.y = y1 * sgf.y * nf;
    ov.z = y2 * sgf.z * nf;
    ov.w = y3 * sgf.w * nf;
    *reinterpret_cast<float4*>(out + row * 128 + 4 * li) = ov;
  }
}

extern "C" void kernel_launch(void* const* d_in, const int* in_sizes, int n_in,
                              void* d_out, int out_size, void* d_ws, size_t ws_size,
                              hipStream_t stream) {
  const float* x     = (const float*)d_in[0];
  const float* signs = (const float*)d_in[1];
  // d_in[2] = wht (unused: Sylvester Hadamard applied as in-register FWHT)
  const float* bnd   = (const float*)d_in[3];
  const float* ctr   = (const float*)d_in[4];
  float* out = (float*)d_out;

  int nrows     = out_size / 128;
  int nrowpairs = nrows / 2;                 // 2 rows per wave
  int blocks = (nrowpairs + 3) / 4;          // 4 waves per block
  if (blocks > 2048) blocks = 2048;
  hipLaunchKernelGGL(tq_kernel, dim3(blocks), dim3(256), 0, stream,
                     x, signs, bnd, ctr, out, nrowpairs);
}

// Round 6
// 75.764 us; speedup vs baseline: 1.5429x; 1.0326x over previous
//
#include <hip/hip_runtime.h>

#define NCELL 512
#define EPSD  1e-8
#define FSCD  0.08838834764831845    // 128**-0.5 (exact double of python repr)

// ---------------- lane-permute primitives ----------------
template<int CTRL>
__device__ __forceinline__ int idpp(int x){
  return __builtin_amdgcn_update_dpp(x, x, CTRL, 0xF, 0xF, false);
}
template<int CTRL>
__device__ __forceinline__ float fdpp(float x){
  return __int_as_float(idpp<CTRL>(__float_as_int(x)));
}
// f32
__device__ __forceinline__ float xorl1(float v){ return fdpp<0xB1>(v); }              // quad_perm [1,0,3,2]
__device__ __forceinline__ float xorl2(float v){ return fdpp<0x4E>(v); }              // quad_perm [2,3,0,1]
__device__ __forceinline__ float xorl4(float v){ return fdpp<0x1B>(fdpp<0x141>(v)); } // xor7(half_mirror) o xor3
__device__ __forceinline__ float xorl8(float v){ return fdpp<0x128>(v); }             // row_ror:8 == xor8
__device__ __forceinline__ void swap16(float &a, float &b){
  asm("v_permlane16_swap_b32 %0, %1" : "+v"(a), "+v"(b));
}
// f64 (per-half DPP)
template<int CTRL>
__device__ __forceinline__ double ddpp(double x){
  return __hiloint2double(idpp<CTRL>(__double2hiint(x)),
                          idpp<CTRL>(__double2loint(x)));
}
__device__ __forceinline__ double dxor1(double v){ return ddpp<0xB1>(v); }
__device__ __forceinline__ double dxor2(double v){ return ddpp<0x4E>(v); }
__device__ __forceinline__ double dxor4(double v){ return ddpp<0x1B>(ddpp<0x141>(v)); }
__device__ __forceinline__ double dxor8(double v){ return ddpp<0x128>(v); }
__device__ __forceinline__ void dswap16(double &a, double &b){
  int al=__double2loint(a), ah=__double2hiint(a);
  int bl=__double2loint(b), bh=__double2hiint(b);
  asm("v_permlane16_swap_b32 %0, %1":"+v"(al),"+v"(bl));
  asm("v_permlane16_swap_b32 %0, %1":"+v"(ah),"+v"(bh));
  a=__hiloint2double(ah,al); b=__hiloint2double(bh,bl);
}
// butterfly reductions over the 32-lane row (bitwise lane-uniform)
__device__ __forceinline__ double dredsum(double v){
  v += dxor1(v); v += dxor2(v); v += dxor4(v); v += dxor8(v);
  double a=v, b=v; dswap16(a,b); return a+b;  // {a,b}={v,partner} either orientation
}
__device__ __forceinline__ double dredmax(double v){
  v = fmax(v,dxor1(v)); v = fmax(v,dxor2(v)); v = fmax(v,dxor4(v)); v = fmax(v,dxor8(v));
  double a=v, b=v; dswap16(a,b); return fmax(a,b);
}

// ---------------- 128-pt FWHT, f64 (forward / decision path) ----------------
__device__ __forceinline__ void dfwht128(double &v0,double &v1,double &v2,double &v3,
                                         double sg1,double sg2,double sg4,double sg8,double m16){
  double a0=v0+v1, a1=v0-v1, a2=v2+v3, a3=v2-v3;   // strides 1,2 in-register
  v0=a0+a2; v2=a0-a2; v1=a1+a3; v3=a1-a3;
  { double o0=dxor1(v0),o1=dxor1(v1),o2=dxor1(v2),o3=dxor1(v3);   // stride 4
    v0=fma(sg1,v0,o0); v1=fma(sg1,v1,o1); v2=fma(sg1,v2,o2); v3=fma(sg1,v3,o3); }
  { double o0=dxor2(v0),o1=dxor2(v1),o2=dxor2(v2),o3=dxor2(v3);   // stride 8
    v0=fma(sg2,v0,o0); v1=fma(sg2,v1,o1); v2=fma(sg2,v2,o2); v3=fma(sg2,v3,o3); }
  { double o0=dxor4(v0),o1=dxor4(v1),o2=dxor4(v2),o3=dxor4(v3);   // stride 16
    v0=fma(sg4,v0,o0); v1=fma(sg4,v1,o1); v2=fma(sg4,v2,o2); v3=fma(sg4,v3,o3); }
  { double o0=dxor8(v0),o1=dxor8(v1),o2=dxor8(v2),o3=dxor8(v3);   // stride 32
    v0=fma(sg8,v0,o0); v1=fma(sg8,v1,o1); v2=fma(sg8,v2,o2); v3=fma(sg8,v3,o3); }
  { double b,c;                                                    // stride 64
    b=v0;c=v0; dswap16(b,c); v0=fma(m16,v0,b+c);
    b=v1;c=v1; dswap16(b,c); v1=fma(m16,v1,b+c);
    b=v2;c=v2; dswap16(b,c); v2=fma(m16,v2,b+c);
    b=v3;c=v3; dswap16(b,c); v3=fma(m16,v3,b+c); }
}

// ---------------- 128-pt FWHT, f32 (inverse path: linear, no decisions) -----
__device__ __forceinline__ void fwht128f(float &v0,float &v1,float &v2,float &v3,
                                         float sg1,float sg2,float sg4,float sg8,float m16){
  float a0=v0+v1, a1=v0-v1, a2=v2+v3, a3=v2-v3;
  v0=a0+a2; v2=a0-a2; v1=a1+a3; v3=a1-a3;
  { float o0=xorl1(v0),o1=xorl1(v1),o2=xorl1(v2),o3=xorl1(v3);
    v0=fmaf(sg1,v0,o0); v1=fmaf(sg1,v1,o1); v2=fmaf(sg1,v2,o2); v3=fmaf(sg1,v3,o3); }
  { float o0=xorl2(v0),o1=xorl2(v1),o2=xorl2(v2),o3=xorl2(v3);
    v0=fmaf(sg2,v0,o0); v1=fmaf(sg2,v1,o1); v2=fmaf(sg2,v2,o2); v3=fmaf(sg2,v3,o3); }
  { float o0=xorl4(v0),o1=xorl4(v1),o2=xorl4(v2),o3=xorl4(v3);
    v0=fmaf(sg4,v0,o0); v1=fmaf(sg4,v1,o1); v2=fmaf(sg4,v2,o2); v3=fmaf(sg4,v3,o3); }
  { float o0=xorl8(v0),o1=xorl8(v1),o2=xorl8(v2),o3=xorl8(v3);
    v0=fmaf(sg8,v0,o0); v1=fmaf(sg8,v1,o1); v2=fmaf(sg8,v2,o2); v3=fmaf(sg8,v3,o3); }
  { float b,c;
    b=v0;c=v0; swap16(b,c); v0=fmaf(m16,v0,b+c);
    b=v1;c=v1; swap16(b,c); v1=fmaf(m16,v1,b+c);
    b=v2;c=v2; swap16(b,c); v2=fmaf(m16,v2,b+c);
    b=v3;c=v3; swap16(b,c); v3=fmaf(m16,v3,b+c); }
}

__global__ __launch_bounds__(256) void tq_kernel(
    const float* __restrict__ x, const float* __restrict__ signs,
    const float* __restrict__ bnd, const float* __restrict__ ctr,
    float* __restrict__ out, int nrowpairs)
{
  // Centroid-in-LUT searchsorted, f64-exact semantics:
  //   cell ic = clamp(fma(rr,A,nls)); sel = (bm1<v)+(b0<v) in {0,1,2}
  //   centroid = {C[pos-1], C[pos], C[pos+1]}[sel]   == Cs[searchsorted(B,v)]
  // NCELL=512: cw=0.0152 < min boundary gap (~0.0169) -> <=1 boundary/cell;
  // even if violated, the off-by-one is confined to small-gap regions where
  // the centroid error (~gap) costs <=1e-3 in the output. bm1-compare covers
  // boundary-on-cell-edge coincidence under ~1e-13 f64 addressing slop.
  __shared__ double2 lutB[NCELL];   // 8 KB  {Bd[pos-1], Bd[pos]}
  __shared__ float4  lutC[NCELL];   // 8 KB  {C[pos-1], C[pos], C[pos+1], 0}
  __shared__ double  Bd[256];       // 2 KB  (255 boundaries + +inf sentinel)
  const int tid = threadIdx.x;
  if (tid < 255)  Bd[tid] = (double)bnd[tid];
  if (tid == 255) Bd[255] = __builtin_inf();
  __syncthreads();

  const double lo    = Bd[0] - 0.01;
  const double cw    = (Bd[254] + 0.01 - lo) * (1.0 / NCELL);
  const double scale = 1.0 / cw;
  const double nls   = -lo * scale;

  // O(1)-depth LUT build: thread i owns pos=i, writes its contiguous cells.
  {
    const int i = tid;
    double bm1 = (i == 0) ? -__builtin_inf() : Bd[i - 1];
    double b0  = Bd[i];                       // i==255 -> +inf sentinel
    float  cm1 = ctr[(i == 0) ? 0 : (i - 1)]; // never selected when i==0 (bm1=-inf)
    float  c0  = ctr[i];
    float  cp1 = ctr[(i == 255) ? 255 : (i + 1)]; // never selected when i==255 (b0=inf)
    int cs = (i == 0)   ? 0     : (int)floor((Bd[i - 1] - lo) * scale) + 1;
    int ce = (i == 255) ? NCELL : (int)floor((Bd[i]     - lo) * scale) + 1;
    cs = max(cs, 0); ce = min(ce, NCELL);
    for (int c = cs; c < ce; ++c) {
      lutB[c] = make_double2(bm1, b0);
      lutC[c] = make_float4(cm1, c0, cp1, 0.f);
    }
  }
  __syncthreads();

  const int l    = tid & 63;
  const int li   = l & 31;
  const int half = l >> 5;
  const int wid  = tid >> 6;
  const double sg1 = (l & 1) ? -1.0 : 1.0;
  const double sg2 = (l & 2) ? -1.0 : 1.0;
  const double sg4 = (l & 4) ? -1.0 : 1.0;
  const double sg8 = (l & 8) ? -1.0 : 1.0;
  const double m16 = (l & 16) ? -2.0 : 0.0;
  const float  sg1f = (l & 1) ? -1.f : 1.f;
  const float  sg2f = (l & 2) ? -1.f : 1.f;
  const float  sg4f = (l & 4) ? -1.f : 1.f;
  const float  sg8f = (l & 8) ? -1.f : 1.f;
  const float  m16f = (l & 16) ? -2.f : 0.f;
  const double inv_maxc = 1.0 / (double)ctr[255];
  const float4 sgf = *reinterpret_cast<const float4*>(signs + 4 * li);

  // returns centroid Cs[searchsorted(B, rr*kd)] ; cell addr via folded scale
  auto qcent = [&](double rr, double A, double kd) -> float {
    double cf = fma(rr, A, nls);
    cf = fmin(fmax(cf, 0.0), (double)(NCELL - 1));
    int ic = (int)cf;
    double v = rr * kd;
    double2 bb = lutB[ic];
    float4  cc = lutC[ic];
    int s = ((bb.x < v) ? 1 : 0) + ((bb.y < v) ? 1 : 0);
    return (s == 0) ? cc.x : ((s == 1) ? cc.y : cc.z);
  };

  for (int t = blockIdx.x * 4 + wid; t < nrowpairs; t += gridDim.x * 4) {
    const int row = 2 * t + half;
    const float4 xv = *reinterpret_cast<const float4*>(x + row * 128 + 4 * li);

    // sign fold exact in f32, widen; rr = unnormalized FWHT(x*s)
    double rr0 = (double)(xv.x * sgf.x);
    double rr1 = (double)(xv.y * sgf.y);
    double rr2 = (double)(xv.z * sgf.z);
    double rr3 = (double)(xv.w * sgf.w);

    // norms = ||x||_2 (f64) + EPS  ((x*s)^2 == x^2 exactly)
    double ss = fma(rr0,rr0, fma(rr1,rr1, fma(rr2,rr2, rr3*rr3)));
    double norms = sqrt(dredsum(ss)) + EPSD;

    dfwht128(rr0, rr1, rr2, rr3, sg1, sg2, sg4, sg8, m16);
    const double k = FSCD / norms;        // x_rot = rr * k   (div #1)

    // stats on rr, scaled by k once
    double ab0=fabs(rr0), ab1=fabs(rr1), ab2=fabs(rr2), ab3=fabs(rr3);
    double xmax  = dredmax(fmax(fmax(ab0,ab1), fmax(ab2,ab3))) * k;
    double asum  = dredsum((ab0+ab1)+(ab2+ab3));
    double xmean = fma(asum * 0.0078125, k, EPSD);
    bool   spiky = xmax > 5.0 * xmean;
    double rms   = xmax * inv_maxc;

    // pass 1: centroid of searchsorted(B, x_rot/(rms+EPS)) via v = rr*(k/(rms+EPS))
    double invd1 = 1.0 / (rms + EPSD);    // div #2
    double kd1 = k * invd1, A1 = kd1 * scale;
    float c10f = qcent(rr0, A1, kd1), c11f = qcent(rr1, A1, kd1),
          c12f = qcent(rr2, A1, kd1), c13f = qcent(rr3, A1, kd1);
    double c10=(double)c10f, c11=(double)c11f, c12=(double)c12f, c13=(double)c13f;

    // gamma refine: num = k * <rr, c>;  den = <c, c> + EPS
    double num = dredsum(fma(rr0,c10, fma(rr1,c11, fma(rr2,c12, rr3*c13)))) * k;
    double den = dredsum(fma(c10,c10, fma(c11,c11, fma(c12,c12, c13*c13)))) + EPSD;
    double gamma1 = num / den;            // div #3

    // pass 2
    double invd2 = 1.0 / (gamma1 + EPSD); // div #4
    double kd2 = k * invd2, A2 = kd2 * scale;
    float c20f = qcent(rr0, A2, kd2), c21f = qcent(rr1, A2, kd2),
          c22f = qcent(rr2, A2, kd2), c23f = qcent(rr3, A2, kd2);

    // reconstruct + inverse rotation in f32 (linear path, no decisions)
    double gamma = spiky ? rms : gamma1;
    float g2f = (float)(gamma * FSCD);
    float y0 = (spiky ? c10f : c20f) * g2f;
    float y1 = (spiky ? c11f : c21f) * g2f;
    float y2 = (spiky ? c12f : c22f) * g2f;
    float y3 = (spiky ? c13f : c23f) * g2f;
    fwht128f(y0, y1, y2, y3, sg1f, sg2f, sg4f, sg8f, m16f);

    const float nf = (float)norms;
    float4 ov;
    ov.x = y0 * sgf.x * nf;
    ov.y = y1 * sgf.y * nf;
    ov.z = y2 * sgf.z * nf;
    ov.w = y3 * sgf.w * nf;
    *reinterpret_cast<float4*>(out + row * 128 + 4 * li) = ov;
  }
}

extern "C" void kernel_launch(void* const* d_in, const int* in_sizes, int n_in,
                              void* d_out, int out_size, void* d_ws, size_t ws_size,
                              hipStream_t stream) {
  const float* x     = (const float*)d_in[0];
  const float* signs = (const float*)d_in[1];
  // d_in[2] = wht (unused: Sylvester Hadamard applied as in-register FWHT)
  const float* bnd   = (const float*)d_in[3];
  const float* ctr   = (const float*)d_in[4];
  float* out = (float*)d_out;

  int nrows     = out_size / 128;
  int nrowpairs = nrows / 2;                 // 2 rows per wave
  int blocks = (nrowpairs + 3) / 4;          // 4 waves per block
  if (blocks > 2048) blocks = 2048;
  hipLaunchKernelGGL(tq_kernel, dim3(blocks), dim3(256), 0, stream,
                     x, signs, bnd, ctr, out, nrowpairs);
}

// Round 7
// 60.629 us; speedup vs baseline: 1.9281x; 1.2496x over previous
//
#include <hip/hip_runtime.h>

#define NCELL 512
#define EPSD  1e-8
#define FSCD  0.08838834764831845    // 128**-0.5 (exact double of python repr)

// ---------------- lane-permute primitives (all within 16-lane DPP rows) -----
template<int CTRL>
__device__ __forceinline__ int idpp(int x){
  return __builtin_amdgcn_update_dpp(x, x, CTRL, 0xF, 0xF, false);
}
template<int CTRL>
__device__ __forceinline__ float fdpp(float x){
  return __int_as_float(idpp<CTRL>(__float_as_int(x)));
}
// f32 lane-xor within 16-lane rows
__device__ __forceinline__ float xorl1(float v){ return fdpp<0xB1>(v); }              // quad_perm [1,0,3,2]
__device__ __forceinline__ float xorl2(float v){ return fdpp<0x4E>(v); }              // quad_perm [2,3,0,1]
__device__ __forceinline__ float xorl4(float v){ return fdpp<0x1B>(fdpp<0x141>(v)); } // half_mirror(x^7) o quad[3,2,1,0](x^3)
__device__ __forceinline__ float xorl8(float v){ return fdpp<0x128>(v); }             // row_ror:8 == x^8 in 16
// f64 (per-half DPP)
template<int CTRL>
__device__ __forceinline__ double ddpp(double x){
  return __hiloint2double(idpp<CTRL>(__double2hiint(x)),
                          idpp<CTRL>(__double2loint(x)));
}
__device__ __forceinline__ double dxor1(double v){ return ddpp<0xB1>(v); }
__device__ __forceinline__ double dxor2(double v){ return ddpp<0x4E>(v); }
__device__ __forceinline__ double dxor4(double v){ return ddpp<0x1B>(ddpp<0x141>(v)); }
__device__ __forceinline__ double dxor8(double v){ return ddpp<0x128>(v); }

// butterfly reductions over a 16-lane row; bitwise lane-uniform (exact commute)
__device__ __forceinline__ double dredsum16(double v){
  v += dxor1(v); v += dxor2(v); v += dxor4(v); v += dxor8(v); return v;
}
__device__ __forceinline__ double dredmax16(double v){
  v = fmax(v,dxor1(v)); v = fmax(v,dxor2(v));
  v = fmax(v,dxor4(v)); v = fmax(v,dxor8(v)); return v;
}

// ------- 128-pt FWHT, 8 elems/lane (e = 8*li + j), 16 lanes/row -------------
// in-register strides 1,2,4 ; cross-lane strides 8,16,32,64 via lane-xor 1,2,4,8
__device__ __forceinline__ void dfwht128_8(double r[8], double sA, double sB,
                                           double sC, double sD){
  double t;
  t=r[0]; r[0]=t+r[1]; r[1]=t-r[1];  t=r[2]; r[2]=t+r[3]; r[3]=t-r[3];
  t=r[4]; r[4]=t+r[5]; r[5]=t-r[5];  t=r[6]; r[6]=t+r[7]; r[7]=t-r[7];
  t=r[0]; r[0]=t+r[2]; r[2]=t-r[2];  t=r[1]; r[1]=t+r[3]; r[3]=t-r[3];
  t=r[4]; r[4]=t+r[6]; r[6]=t-r[6];  t=r[5]; r[5]=t+r[7]; r[7]=t-r[7];
  t=r[0]; r[0]=t+r[4]; r[4]=t-r[4];  t=r[1]; r[1]=t+r[5]; r[5]=t-r[5];
  t=r[2]; r[2]=t+r[6]; r[6]=t-r[6];  t=r[3]; r[3]=t+r[7]; r[7]=t-r[7];
  #pragma unroll
  for (int j=0;j<8;++j){ double o=dxor1(r[j]); r[j]=fma(sA, r[j], o); }
  #pragma unroll
  for (int j=0;j<8;++j){ double o=dxor2(r[j]); r[j]=fma(sB, r[j], o); }
  #pragma unroll
  for (int j=0;j<8;++j){ double o=dxor4(r[j]); r[j]=fma(sC, r[j], o); }
  #pragma unroll
  for (int j=0;j<8;++j){ double o=dxor8(r[j]); r[j]=fma(sD, r[j], o); }
}
__device__ __forceinline__ void fwht128f_8(float r[8], float sA, float sB,
                                           float sC, float sD){
  float t;
  t=r[0]; r[0]=t+r[1]; r[1]=t-r[1];  t=r[2]; r[2]=t+r[3]; r[3]=t-r[3];
  t=r[4]; r[4]=t+r[5]; r[5]=t-r[5];  t=r[6]; r[6]=t+r[7]; r[7]=t-r[7];
  t=r[0]; r[0]=t+r[2]; r[2]=t-r[2];  t=r[1]; r[1]=t+r[3]; r[3]=t-r[3];
  t=r[4]; r[4]=t+r[6]; r[6]=t-r[6];  t=r[5]; r[5]=t+r[7]; r[7]=t-r[7];
  t=r[0]; r[0]=t+r[4]; r[4]=t-r[4];  t=r[1]; r[1]=t+r[5]; r[5]=t-r[5];
  t=r[2]; r[2]=t+r[6]; r[6]=t-r[6];  t=r[3]; r[3]=t+r[7]; r[7]=t-r[7];
  #pragma unroll
  for (int j=0;j<8;++j){ float o=xorl1(r[j]); r[j]=fmaf(sA, r[j], o); }
  #pragma unroll
  for (int j=0;j<8;++j){ float o=xorl2(r[j]); r[j]=fmaf(sB, r[j], o); }
  #pragma unroll
  for (int j=0;j<8;++j){ float o=xorl4(r[j]); r[j]=fmaf(sC, r[j], o); }
  #pragma unroll
  for (int j=0;j<8;++j){ float o=xorl8(r[j]); r[j]=fmaf(sD, r[j], o); }
}

__global__ __launch_bounds__(256) void tq_kernel(
    const float* __restrict__ x, const float* __restrict__ signs,
    const float* __restrict__ bnd, const float* __restrict__ ctr,
    float* __restrict__ out, int nquads)
{
  // Centroid-in-LUT searchsorted, f64-exact compare semantics (as R6):
  //   cell ic (f32 addressing, +/-1-cell slop absorbed by the 2-compare window)
  //   sel = (bm1<v)+(b0<v); centroid = {C[pos-1],C[pos],C[pos+1]}[sel]
  __shared__ double2 lutB[NCELL];   // 8 KB  {Bd[pos-1], Bd[pos]}
  __shared__ float4  lutC[NCELL];   // 8 KB  {C[pos-1], C[pos], C[pos+1], 0}
  __shared__ double  Bd[256];       // 2 KB  (255 boundaries + +inf sentinel)
  const int tid = threadIdx.x;
  if (tid < 255)  Bd[tid] = (double)bnd[tid];
  if (tid == 255) Bd[255] = __builtin_inf();
  __syncthreads();

  const double lo    = Bd[0] - 0.01;
  const double cw    = (Bd[254] + 0.01 - lo) * (1.0 / NCELL);
  const double scale = 1.0 / cw;
  const double nls   = -lo * scale;

  // O(1)-depth LUT build: thread i owns pos=i, writes its contiguous cells.
  {
    const int i = tid;
    double bm1 = (i == 0) ? -__builtin_inf() : Bd[i - 1];
    double b0  = Bd[i];                           // i==255 -> +inf sentinel
    float  cm1 = ctr[(i == 0) ? 0 : (i - 1)];     // unselectable when i==0
    float  c0  = ctr[i];
    float  cp1 = ctr[(i == 255) ? 255 : (i + 1)]; // unselectable when i==255
    int cs = (i == 0)   ? 0     : (int)floor((Bd[i - 1] - lo) * scale) + 1;
    int ce = (i == 255) ? NCELL : (int)floor((Bd[i]     - lo) * scale) + 1;
    cs = max(cs, 0); ce = min(ce, NCELL);
    for (int c = cs; c < ce; ++c) {
      lutB[c] = make_double2(bm1, b0);
      lutC[c] = make_float4(cm1, c0, cp1, 0.f);
    }
  }
  __syncthreads();

  const int l   = tid & 63;
  const int li  = l & 15;         // lane within 16-lane row
  const int rw  = (l >> 4) & 3;   // row within wave (4 rows/wave)
  const int wid = tid >> 6;
  const double sA = (l & 1) ? -1.0 : 1.0;
  const double sB = (l & 2) ? -1.0 : 1.0;
  const double sC = (l & 4) ? -1.0 : 1.0;
  const double sD = (l & 8) ? -1.0 : 1.0;
  const float  sAf = (l & 1) ? -1.f : 1.f;
  const float  sBf = (l & 2) ? -1.f : 1.f;
  const float  sCf = (l & 4) ? -1.f : 1.f;
  const float  sDf = (l & 8) ? -1.f : 1.f;
  const double inv_maxc = 1.0 / (double)ctr[255];
  const float  nlsf = (float)nls;
  const float  icmax = (float)(NCELL - 1);

  const float4 sga = *reinterpret_cast<const float4*>(signs + 8 * li);
  const float4 sgb = *reinterpret_cast<const float4*>(signs + 8 * li + 4);

  // centroid of searchsorted(B, rr*kd): f32 cell addr, f64 compares
  auto qcent = [&](double rr, float rrf, float Af, double kd) -> float {
    float cf = fmaf(rrf, Af, nlsf);
    cf = fminf(fmaxf(cf, 0.0f), icmax);
    int ic = (int)cf;
    double v = rr * kd;
    double2 bb = lutB[ic];
    float4  cc = lutC[ic];
    int s = ((bb.x < v) ? 1 : 0) + ((bb.y < v) ? 1 : 0);
    return (s == 0) ? cc.x : ((s == 1) ? cc.y : cc.z);
  };

  for (int t = blockIdx.x * 4 + wid; t < nquads; t += gridDim.x * 4) {
    const int row = 4 * t + rw;
    const float* xp = x + row * 128 + 8 * li;
    const float4 xa = *reinterpret_cast<const float4*>(xp);
    const float4 xb = *reinterpret_cast<const float4*>(xp + 4);

    // sign fold exact in f32, widen; r = unnormalized FWHT(x*s)
    double r[8];
    r[0] = (double)(xa.x * sga.x);  r[1] = (double)(xa.y * sga.y);
    r[2] = (double)(xa.z * sga.z);  r[3] = (double)(xa.w * sga.w);
    r[4] = (double)(xb.x * sgb.x);  r[5] = (double)(xb.y * sgb.y);
    r[6] = (double)(xb.z * sgb.z);  r[7] = (double)(xb.w * sgb.w);

    // norms = ||x||_2 (f64) + EPS
    double ss = r[0] * r[0];
    #pragma unroll
    for (int j = 1; j < 8; ++j) ss = fma(r[j], r[j], ss);
    double norms = sqrt(dredsum16(ss)) + EPSD;

    dfwht128_8(r, sA, sB, sC, sD);
    const double k = FSCD / norms;        // x_rot = r * k   (div #1)

    // stats
    double mx = fabs(r[0]), as = mx;
    #pragma unroll
    for (int j = 1; j < 8; ++j) { double a = fabs(r[j]); mx = fmax(mx, a); as += a; }
    double xmax  = dredmax16(mx) * k;
    double xmean = fma(dredsum16(as) * 0.0078125, k, EPSD);
    bool   spiky = xmax > 5.0 * xmean;
    double rms   = xmax * inv_maxc;

    float rrf[8];
    #pragma unroll
    for (int j = 0; j < 8; ++j) rrf[j] = (float)r[j];

    // pass 1: v = r*(k/(rms+EPS))
    double invd1 = 1.0 / (rms + EPSD);    // div #2
    double kd1 = k * invd1;
    float  A1f = (float)(kd1 * scale);
    float c1f[8];
    #pragma unroll
    for (int j = 0; j < 8; ++j) c1f[j] = qcent(r[j], rrf[j], A1f, kd1);

    // gamma refine: num = k * <r, c>;  den = <c, c> + EPS
    double num_l = 0.0, den_l = 0.0;
    #pragma unroll
    for (int j = 0; j < 8; ++j) {
      double cd = (double)c1f[j];
      num_l = fma(r[j], cd, num_l);
      den_l = fma(cd, cd, den_l);
    }
    double num = dredsum16(num_l) * k;
    double den = dredsum16(den_l) + EPSD;
    double gamma1 = num / den;            // div #3

    // pass 2
    double invd2 = 1.0 / (gamma1 + EPSD); // div #4
    double kd2 = k * invd2;
    float  A2f = (float)(kd2 * scale);
    float c2f[8];
    #pragma unroll
    for (int j = 0; j < 8; ++j) c2f[j] = qcent(r[j], rrf[j], A2f, kd2);

    // reconstruct + inverse rotation in f32 (linear path, no decisions)
    double gamma = spiky ? rms : gamma1;
    float g2f = (float)(gamma * FSCD);
    float y[8];
    #pragma unroll
    for (int j = 0; j < 8; ++j) y[j] = (spiky ? c1f[j] : c2f[j]) * g2f;
    fwht128f_8(y, sAf, sBf, sCf, sDf);

    const float nf = (float)norms;
    float4 oa, ob;
    oa.x = y[0] * sga.x * nf;  oa.y = y[1] * sga.y * nf;
    oa.z = y[2] * sga.z * nf;  oa.w = y[3] * sga.w * nf;
    ob.x = y[4] * sgb.x * nf;  ob.y = y[5] * sgb.y * nf;
    ob.z = y[6] * sgb.z * nf;  ob.w = y[7] * sgb.w * nf;
    float* op = out + row * 128 + 8 * li;
    *reinterpret_cast<float4*>(op)     = oa;
    *reinterpret_cast<float4*>(op + 4) = ob;
  }
}

extern "C" void kernel_launch(void* const* d_in, const int* in_sizes, int n_in,
                              void* d_out, int out_size, void* d_ws, size_t ws_size,
                              hipStream_t stream) {
  const float* x     = (const float*)d_in[0];
  const float* signs = (const float*)d_in[1];
  // d_in[2] = wht (unused: Sylvester Hadamard applied as in-register FWHT)
  const float* bnd   = (const float*)d_in[3];
  const float* ctr   = (const float*)d_in[4];
  float* out = (float*)d_out;

  int nrows  = out_size / 128;
  int nquads = nrows / 4;                    // 4 rows per wave
  int blocks = (nquads + 3) / 4;             // 4 waves per block
  if (blocks > 2048) blocks = 2048;
  hipLaunchKernelGGL(tq_kernel, dim3(blocks), dim3(256), 0, stream,
                     x, signs, bnd, ctr, out, nquads);
}

// Round 8
// 50.781 us; speedup vs baseline: 2.3020x; 1.1939x over previous
//
#include <hip/hip_runtime.h>

#define NCELL 512
#define EPSD  1e-8
#define FSCD  0.08838834764831845    // 128**-0.5 (exact double of python repr)

// ---------------- lane-permute primitives (all within 16-lane DPP rows) -----
template<int CTRL>
__device__ __forceinline__ int idpp(int x){
  return __builtin_amdgcn_update_dpp(x, x, CTRL, 0xF, 0xF, false);
}
template<int CTRL>
__device__ __forceinline__ float fdpp(float x){
  return __int_as_float(idpp<CTRL>(__float_as_int(x)));
}
// f32 lane-xor within 16-lane rows
__device__ __forceinline__ float xorl1(float v){ return fdpp<0xB1>(v); }              // quad_perm [1,0,3,2]
__device__ __forceinline__ float xorl2(float v){ return fdpp<0x4E>(v); }              // quad_perm [2,3,0,1]
__device__ __forceinline__ float xorl4(float v){ return fdpp<0x1B>(fdpp<0x141>(v)); } // half_mirror(x^7) o quad[3,2,1,0](x^3)
__device__ __forceinline__ float xorl8(float v){ return fdpp<0x128>(v); }             // row_ror:8 == x^8 in 16
// f64 (per-half DPP)
template<int CTRL>
__device__ __forceinline__ double ddpp(double x){
  return __hiloint2double(idpp<CTRL>(__double2hiint(x)),
                          idpp<CTRL>(__double2loint(x)));
}
__device__ __forceinline__ double dxor1(double v){ return ddpp<0xB1>(v); }
__device__ __forceinline__ double dxor2(double v){ return ddpp<0x4E>(v); }
__device__ __forceinline__ double dxor4(double v){ return ddpp<0x1B>(ddpp<0x141>(v)); }
__device__ __forceinline__ double dxor8(double v){ return ddpp<0x128>(v); }

// butterfly reductions over a 16-lane row; bitwise lane-uniform (exact commute)
__device__ __forceinline__ double dredsum16(double v){
  v += dxor1(v); v += dxor2(v); v += dxor4(v); v += dxor8(v); return v;
}
__device__ __forceinline__ double dredmax16(double v){
  v = fmax(v,dxor1(v)); v = fmax(v,dxor2(v));
  v = fmax(v,dxor4(v)); v = fmax(v,dxor8(v)); return v;
}

// ------- 128-pt FWHT, 8 elems/lane (e = 8*li + j), 16 lanes/row -------------
// in-register strides 1,2,4 ; cross-lane strides 8,16,32,64 via lane-xor 1,2,4,8
__device__ __forceinline__ void dfwht128_8(double r[8], double sA, double sB,
                                           double sC, double sD){
  double t;
  t=r[0]; r[0]=t+r[1]; r[1]=t-r[1];  t=r[2]; r[2]=t+r[3]; r[3]=t-r[3];
  t=r[4]; r[4]=t+r[5]; r[5]=t-r[5];  t=r[6]; r[6]=t+r[7]; r[7]=t-r[7];
  t=r[0]; r[0]=t+r[2]; r[2]=t-r[2];  t=r[1]; r[1]=t+r[3]; r[3]=t-r[3];
  t=r[4]; r[4]=t+r[6]; r[6]=t-r[6];  t=r[5]; r[5]=t+r[7]; r[7]=t-r[7];
  t=r[0]; r[0]=t+r[4]; r[4]=t-r[4];  t=r[1]; r[1]=t+r[5]; r[5]=t-r[5];
  t=r[2]; r[2]=t+r[6]; r[6]=t-r[6];  t=r[3]; r[3]=t+r[7]; r[7]=t-r[7];
  #pragma unroll
  for (int j=0;j<8;++j){ double o=dxor1(r[j]); r[j]=fma(sA, r[j], o); }
  #pragma unroll
  for (int j=0;j<8;++j){ double o=dxor2(r[j]); r[j]=fma(sB, r[j], o); }
  #pragma unroll
  for (int j=0;j<8;++j){ double o=dxor4(r[j]); r[j]=fma(sC, r[j], o); }
  #pragma unroll
  for (int j=0;j<8;++j){ double o=dxor8(r[j]); r[j]=fma(sD, r[j], o); }
}
__device__ __forceinline__ void fwht128f_8(float r[8], float sA, float sB,
                                           float sC, float sD){
  float t;
  t=r[0]; r[0]=t+r[1]; r[1]=t-r[1];  t=r[2]; r[2]=t+r[3]; r[3]=t-r[3];
  t=r[4]; r[4]=t+r[5]; r[5]=t-r[5];  t=r[6]; r[6]=t+r[7]; r[7]=t-r[7];
  t=r[0]; r[0]=t+r[2]; r[2]=t-r[2];  t=r[1]; r[1]=t+r[3]; r[3]=t-r[3];
  t=r[4]; r[4]=t+r[6]; r[6]=t-r[6];  t=r[5]; r[5]=t+r[7]; r[7]=t-r[7];
  t=r[0]; r[0]=t+r[4]; r[4]=t-r[4];  t=r[1]; r[1]=t+r[5]; r[5]=t-r[5];
  t=r[2]; r[2]=t+r[6]; r[6]=t-r[6];  t=r[3]; r[3]=t+r[7]; r[7]=t-r[7];
  #pragma unroll
  for (int j=0;j<8;++j){ float o=xorl1(r[j]); r[j]=fmaf(sA, r[j], o); }
  #pragma unroll
  for (int j=0;j<8;++j){ float o=xorl2(r[j]); r[j]=fmaf(sB, r[j], o); }
  #pragma unroll
  for (int j=0;j<8;++j){ float o=xorl4(r[j]); r[j]=fmaf(sC, r[j], o); }
  #pragma unroll
  for (int j=0;j<8;++j){ float o=xorl8(r[j]); r[j]=fmaf(sD, r[j], o); }
}

__global__ __launch_bounds__(256) void tq_kernel(
    const float* __restrict__ x, const float* __restrict__ signs,
    const float* __restrict__ bnd, const float* __restrict__ ctr,
    float* __restrict__ out, int nquads)
{
  // One-gather searchsorted LUT, f64-exact semantics.
  // Cell c's REACH (set of v that can address it after f32 slop + clamping):
  //   [wl, wr) = [lo + c*cw - eps, lo + (c+1)*cw + eps), wl=-inf at c=0,
  //   wr=+inf at c=NCELL-1.  gap_min(0.0169) > cw+2*eps(0.0096) => at most
  //   ONE boundary b* in reach.  Entry {f64 b* (+inf if none), C[n_lo],
  //   C[n_lo+1]} with n_lo = #{B < wl}.  Then for any v in reach:
  //   searchsorted(B,v) = n_lo + (b* < v)  -- exact, single f64 compare.
  __shared__ int4   lutE[NCELL];   // 8 KB  {b*_lo32, b*_hi32, C[n_lo], C[n_lo+1]}
  __shared__ double Bd[256];       // 2 KB  (255 boundaries + +inf sentinel)
  const int tid = threadIdx.x;
  if (tid < 255)  Bd[tid] = (double)bnd[tid];
  if (tid == 255) Bd[255] = __builtin_inf();
  __syncthreads();

  const double lo    = Bd[0] - 0.01;
  const double cw    = (Bd[254] + 0.01 - lo) * (1.0 / NCELL);
  const double scale = 1.0 / cw;
  const double nls   = -lo * scale;
  const double epsg  = cw * 1e-3;       // >> f32 addressing slop (~2e-4 cells)

  for (int c = tid; c < NCELL; c += 256) {
    double wl = (c == 0)         ? -__builtin_inf() : fma((double)c,     cw, lo) - epsg;
    double wr = (c == NCELL - 1) ?  __builtin_inf() : fma((double)(c+1), cw, lo) + epsg;
    int n = 0;
    #pragma unroll
    for (int s = 128; s; s >>= 1) n += (Bd[n + s - 1] < wl) ? s : 0;  // n = #{B < wl}
    double b  = Bd[n];                  // +inf sentinel at n==255
    bool  has = (b < wr);               // unique boundary in reach, if any
    double bs = has ? b : __builtin_inf();
    int4 e;
    e.x = __double2loint(bs);
    e.y = __double2hiint(bs);
    e.z = __float_as_int(ctr[n]);
    e.w = __float_as_int(ctr[has ? (n + 1) : n]);   // has => n<=254
    lutE[c] = e;
  }
  __syncthreads();

  const int l   = tid & 63;
  const int li  = l & 15;         // lane within 16-lane row
  const int rw  = (l >> 4) & 3;   // row within wave (4 rows/wave)
  const int wid = tid >> 6;
  const double sA = (l & 1) ? -1.0 : 1.0;
  const double sB = (l & 2) ? -1.0 : 1.0;
  const double sC = (l & 4) ? -1.0 : 1.0;
  const double sD = (l & 8) ? -1.0 : 1.0;
  const float  sAf = (l & 1) ? -1.f : 1.f;
  const float  sBf = (l & 2) ? -1.f : 1.f;
  const float  sCf = (l & 4) ? -1.f : 1.f;
  const float  sDf = (l & 8) ? -1.f : 1.f;
  const double inv_maxc = 1.0 / (double)ctr[255];
  const float  nlsf  = (float)nls;
  const float  icmax = (float)(NCELL - 1);

  const float4 sga = *reinterpret_cast<const float4*>(signs + 8 * li);
  const float4 sgb = *reinterpret_cast<const float4*>(signs + 8 * li + 4);

  // centroid C[searchsorted(B, rr*kd)]: f32 cell addr, ONE gather, ONE f64 cmp
  auto qcent = [&](double rr, float rrf, float Af, double kd) -> float {
    float cf = fmaf(rrf, Af, nlsf);
    cf = fminf(fmaxf(cf, 0.0f), icmax);
    int ic = (int)cf;
    int4 e = lutE[ic];
    double bstar = __hiloint2double(e.y, e.x);
    double v = rr * kd;
    return __int_as_float((bstar < v) ? e.w : e.z);
  };

  for (int t = blockIdx.x * 4 + wid; t < nquads; t += gridDim.x * 4) {
    const int row = 4 * t + rw;
    const float* xp = x + row * 128 + 8 * li;
    const float4 xa = *reinterpret_cast<const float4*>(xp);
    const float4 xb = *reinterpret_cast<const float4*>(xp + 4);

    // sign fold exact in f32, widen; r = unnormalized FWHT(x*s)
    double r[8];
    r[0] = (double)(xa.x * sga.x);  r[1] = (double)(xa.y * sga.y);
    r[2] = (double)(xa.z * sga.z);  r[3] = (double)(xa.w * sga.w);
    r[4] = (double)(xb.x * sgb.x);  r[5] = (double)(xb.y * sgb.y);
    r[6] = (double)(xb.z * sgb.z);  r[7] = (double)(xb.w * sgb.w);

    // norms = ||x||_2 (f64) + EPS
    double ss = r[0] * r[0];
    #pragma unroll
    for (int j = 1; j < 8; ++j) ss = fma(r[j], r[j], ss);
    double norms = sqrt(dredsum16(ss)) + EPSD;

    dfwht128_8(r, sA, sB, sC, sD);
    const double k = FSCD / norms;        // x_rot = r * k   (div #1)

    // stats
    double mx = fabs(r[0]), as = mx;
    #pragma unroll
    for (int j = 1; j < 8; ++j) { double a = fabs(r[j]); mx = fmax(mx, a); as += a; }
    double xmax  = dredmax16(mx) * k;
    double xmean = fma(dredsum16(as) * 0.0078125, k, EPSD);
    bool   spiky = xmax > 5.0 * xmean;
    double rms   = xmax * inv_maxc;

    float rrf[8];
    #pragma unroll
    for (int j = 0; j < 8; ++j) rrf[j] = (float)r[j];

    // pass 1: v = r*(k/(rms+EPS))
    double invd1 = 1.0 / (rms + EPSD);    // div #2
    double kd1 = k * invd1;
    float  A1f = (float)(kd1 * scale);
    float c1f[8];
    #pragma unroll
    for (int j = 0; j < 8; ++j) c1f[j] = qcent(r[j], rrf[j], A1f, kd1);

    // gamma refine: num = k * <r, c>;  den = <c, c> + EPS
    double num_l = 0.0, den_l = 0.0;
    #pragma unroll
    for (int j = 0; j < 8; ++j) {
      double cd = (double)c1f[j];
      num_l = fma(r[j], cd, num_l);
      den_l = fma(cd, cd, den_l);
    }
    double num = dredsum16(num_l) * k;
    double den = dredsum16(den_l) + EPSD;
    double gamma1 = num / den;            // div #3

    // pass 2
    double invd2 = 1.0 / (gamma1 + EPSD); // div #4
    double kd2 = k * invd2;
    float  A2f = (float)(kd2 * scale);
    float c2f[8];
    #pragma unroll
    for (int j = 0; j < 8; ++j) c2f[j] = qcent(r[j], rrf[j], A2f, kd2);

    // reconstruct + inverse rotation in f32 (linear path, no decisions)
    double gamma = spiky ? rms : gamma1;
    float g2f = (float)(gamma * FSCD);
    float y[8];
    #pragma unroll
    for (int j = 0; j < 8; ++j) y[j] = (spiky ? c1f[j] : c2f[j]) * g2f;
    fwht128f_8(y, sAf, sBf, sCf, sDf);

    const float nf = (float)norms;
    float4 oa, ob;
    oa.x = y[0] * sga.x * nf;  oa.y = y[1] * sga.y * nf;
    oa.z = y[2] * sga.z * nf;  oa.w = y[3] * sga.w * nf;
    ob.x = y[4] * sgb.x * nf;  ob.y = y[5] * sgb.y * nf;
    ob.z = y[6] * sgb.z * nf;  ob.w = y[7] * sgb.w * nf;
    float* op = out + row * 128 + 8 * li;
    *reinterpret_cast<float4*>(op)     = oa;
    *reinterpret_cast<float4*>(op + 4) = ob;
  }
}

extern "C" void kernel_launch(void* const* d_in, const int* in_sizes, int n_in,
                              void* d_out, int out_size, void* d_ws, size_t ws_size,
                              hipStream_t stream) {
  const float* x     = (const float*)d_in[0];
  const float* signs = (const float*)d_in[1];
  // d_in[2] = wht (unused: Sylvester Hadamard applied as in-register FWHT)
  const float* bnd   = (const float*)d_in[3];
  const float* ctr   = (const float*)d_in[4];
  float* out = (float*)d_out;

  int nrows  = out_size / 128;
  int nquads = nrows / 4;                    // 4 rows per wave
  int blocks = (nquads + 3) / 4;             // 4 waves per block
  if (blocks > 2048) blocks = 2048;
  hipLaunchKernelGGL(tq_kernel, dim3(blocks), dim3(256), 0, stream,
                     x, signs, bnd, ctr, out, nquads);
}

// Round 9
// 43.420 us; speedup vs baseline: 2.6922x; 1.1695x over previous
//
#include <hip/hip_runtime.h>

#define NCELL 512
#define EPSD  1e-8
#define FSCD  0.08838834764831845    // 128**-0.5 (exact double of python repr)

// ---------------- lane-permute primitives (all within 16-lane DPP rows) -----
template<int CTRL>
__device__ __forceinline__ int idpp(int x){
  return __builtin_amdgcn_update_dpp(x, x, CTRL, 0xF, 0xF, false);
}
template<int CTRL>
__device__ __forceinline__ float fdpp(float x){
  return __int_as_float(idpp<CTRL>(__float_as_int(x)));
}
// f32 lane-xor within 16-lane rows
__device__ __forceinline__ float xorl1(float v){ return fdpp<0xB1>(v); }              // quad_perm [1,0,3,2]
__device__ __forceinline__ float xorl2(float v){ return fdpp<0x4E>(v); }              // quad_perm [2,3,0,1]
__device__ __forceinline__ float xorl4(float v){ return fdpp<0x1B>(fdpp<0x141>(v)); } // half_mirror(x^7) o quad[3,2,1,0](x^3)
__device__ __forceinline__ float xorl8(float v){ return fdpp<0x128>(v); }             // row_ror:8 == x^8 in 16

// f32 butterfly reductions over a 16-lane row; bitwise lane-uniform.
// NOTE: pure xor-DPP butterflies, no permlane16_swap anywhere (the R1/R2
// failure is attributed to the swap16(a,b) two-reg asm being coalesced).
__device__ __forceinline__ float redsum16f(float v){
  v += xorl1(v); v += xorl2(v); v += xorl4(v); v += xorl8(v); return v;
}
__device__ __forceinline__ float redmax16f(float v){
  v = fmaxf(v,xorl1(v)); v = fmaxf(v,xorl2(v));
  v = fmaxf(v,xorl4(v)); v = fmaxf(v,xorl8(v)); return v;
}

// ------- 128-pt FWHT, f32, 8 elems/lane (e = 8*li + j), 16 lanes/row --------
// in-register strides 1,2,4 ; cross-lane strides 8,16,32,64 via lane-xor 1,2,4,8
__device__ __forceinline__ void fwht128f_8(float r[8], float sA, float sB,
                                           float sC, float sD){
  float t;
  t=r[0]; r[0]=t+r[1]; r[1]=t-r[1];  t=r[2]; r[2]=t+r[3]; r[3]=t-r[3];
  t=r[4]; r[4]=t+r[5]; r[5]=t-r[5];  t=r[6]; r[6]=t+r[7]; r[7]=t-r[7];
  t=r[0]; r[0]=t+r[2]; r[2]=t-r[2];  t=r[1]; r[1]=t+r[3]; r[3]=t-r[3];
  t=r[4]; r[4]=t+r[6]; r[6]=t-r[6];  t=r[5]; r[5]=t+r[7]; r[7]=t-r[7];
  t=r[0]; r[0]=t+r[4]; r[4]=t-r[4];  t=r[1]; r[1]=t+r[5]; r[5]=t-r[5];
  t=r[2]; r[2]=t+r[6]; r[6]=t-r[6];  t=r[3]; r[3]=t+r[7]; r[7]=t-r[7];
  #pragma unroll
  for (int j=0;j<8;++j){ float o=xorl1(r[j]); r[j]=fmaf(sA, r[j], o); }
  #pragma unroll
  for (int j=0;j<8;++j){ float o=xorl2(r[j]); r[j]=fmaf(sB, r[j], o); }
  #pragma unroll
  for (int j=0;j<8;++j){ float o=xorl4(r[j]); r[j]=fmaf(sC, r[j], o); }
  #pragma unroll
  for (int j=0;j<8;++j){ float o=xorl8(r[j]); r[j]=fmaf(sD, r[j], o); }
}

__global__ __launch_bounds__(256) void tq_kernel(
    const float* __restrict__ x, const float* __restrict__ signs,
    const float* __restrict__ bnd, const float* __restrict__ ctr,
    float* __restrict__ out, int nquads)
{
  // One-gather searchsorted LUT (R8 design, unchanged): cell reach contains
  // at most ONE boundary b*; entry {f64 b* (+inf if none), C[n_lo], C[n_lo+1]}
  // => searchsorted(B,v) centroid = (b* < v) ? C[n_lo+1] : C[n_lo]. Exact.
  __shared__ int4   lutE[NCELL];   // 8 KB  {b*_lo32, b*_hi32, C[n_lo], C[n_lo+1]}
  __shared__ double Bd[256];       // 2 KB  (255 boundaries + +inf sentinel)
  const int tid = threadIdx.x;
  if (tid < 255)  Bd[tid] = (double)bnd[tid];
  if (tid == 255) Bd[255] = __builtin_inf();
  __syncthreads();

  const double lo    = Bd[0] - 0.01;
  const double cw    = (Bd[254] + 0.01 - lo) * (1.0 / NCELL);
  const double scale = 1.0 / cw;
  const double nls   = -lo * scale;
  const double epsg  = cw * 1e-3;       // >> f32 addressing slop (~2e-4 cells)

  for (int c = tid; c < NCELL; c += 256) {
    double wl = (c == 0)         ? -__builtin_inf() : fma((double)c,     cw, lo) - epsg;
    double wr = (c == NCELL - 1) ?  __builtin_inf() : fma((double)(c+1), cw, lo) + epsg;
    int n = 0;
    #pragma unroll
    for (int s = 128; s; s >>= 1) n += (Bd[n + s - 1] < wl) ? s : 0;  // n = #{B < wl}
    double b  = Bd[n];                  // +inf sentinel at n==255
    bool  has = (b < wr);               // unique boundary in reach, if any
    double bs = has ? b : __builtin_inf();
    int4 e;
    e.x = __double2loint(bs);
    e.y = __double2hiint(bs);
    e.z = __float_as_int(ctr[n]);
    e.w = __float_as_int(ctr[has ? (n + 1) : n]);   // has => n<=254
    lutE[c] = e;
  }
  __syncthreads();

  const int l   = tid & 63;
  const int li  = l & 15;         // lane within 16-lane row
  const int rw  = (l >> 4) & 3;   // row within wave (4 rows/wave)
  const int wid = tid >> 6;
  const float sAf = (l & 1) ? -1.f : 1.f;
  const float sBf = (l & 2) ? -1.f : 1.f;
  const float sCf = (l & 4) ? -1.f : 1.f;
  const float sDf = (l & 8) ? -1.f : 1.f;
  const double inv_maxc = 1.0 / (double)ctr[255];
  const float  nlsf  = (float)nls;
  const float  icmax = (float)(NCELL - 1);

  const float4 sga = *reinterpret_cast<const float4*>(signs + 8 * li);
  const float4 sgb = *reinterpret_cast<const float4*>(signs + 8 * li + 4);

  // centroid C[searchsorted(B, r*kd)]: f32 cell addr, ONE gather, ONE f64 cmp
  auto qcent = [&](float rf, float Af, double kd) -> float {
    float cf = fmaf(rf, Af, nlsf);
    cf = fminf(fmaxf(cf, 0.0f), icmax);
    int ic = (int)cf;
    int4 e = lutE[ic];
    double bstar = __hiloint2double(e.y, e.x);
    double v = (double)rf * kd;
    return __int_as_float((bstar < v) ? e.w : e.z);
  };

  const int stride = gridDim.x * 4;
  int t = blockIdx.x * 4 + wid;
  if (t >= nquads) return;

  // software pipeline: prefetch next iteration's x while computing current
  const float* xp = x + (4 * t + rw) * 128 + 8 * li;
  float4 xa = *reinterpret_cast<const float4*>(xp);
  float4 xb = *reinterpret_cast<const float4*>(xp + 4);

  while (true) {
    const int tn = t + stride;
    const bool more = (tn < nquads);
    // clamped prefetch address (valid memory; discarded if !more)
    const int tpf = more ? tn : t;
    const float* np_ = x + (4 * tpf + rw) * 128 + 8 * li;
    float4 na = *reinterpret_cast<const float4*>(np_);
    float4 nb = *reinterpret_cast<const float4*>(np_ + 4);

    // sign fold exact in f32; r = unnormalized f32 FWHT(x*s)
    float r[8];
    r[0] = xa.x * sga.x;  r[1] = xa.y * sga.y;
    r[2] = xa.z * sga.z;  r[3] = xa.w * sga.w;
    r[4] = xb.x * sgb.x;  r[5] = xb.y * sgb.y;
    r[6] = xb.z * sgb.z;  r[7] = xb.w * sgb.w;

    // norms = ||x||_2 + EPS  (f32 squares, f32 reduction, f64 sqrt;
    // norm is a uniform factor -> decisions scale-invariant)
    float ssf = r[0] * r[0];
    #pragma unroll
    for (int j = 1; j < 8; ++j) ssf = fmaf(r[j], r[j], ssf);
    double norms = sqrt((double)redsum16f(ssf)) + EPSD;

    fwht128f_8(r, sAf, sBf, sCf, sDf);
    const double k = FSCD / norms;        // x_rot = r * k   (div #1)

    // stats: f32 max is exact selection; f32 |sum| err ~5e-7 (subdominant
    // to r's ~1e-6); spiky compare in f64 on the widened values
    float mxf = fabsf(r[0]), asf = mxf;
    #pragma unroll
    for (int j = 1; j < 8; ++j) {
      float a = fabsf(r[j]); mxf = fmaxf(mxf, a); asf += a;
    }
    double xmax  = (double)redmax16f(mxf) * k;
    double xmean = fma((double)redsum16f(asf) * 0.0078125, k, EPSD);
    bool   spiky = xmax > 5.0 * xmean;
    double rms   = xmax * inv_maxc;

    // pass 1: v = r*(k/(rms+EPS))
    double invd1 = 1.0 / (rms + EPSD);    // div #2
    double kd1 = k * invd1;
    float  A1f = (float)(kd1 * scale);
    float c1f[8];
    #pragma unroll
    for (int j = 0; j < 8; ++j) c1f[j] = qcent(r[j], A1f, kd1);

    // gamma refine in f32 (gamma1 rel err ~1e-7: bucket-flip cost <=0.03,
    // output scale err ~1e-6 -- harmless); final division in f64
    float numf = 0.f, denf = 0.f;
    #pragma unroll
    for (int j = 0; j < 8; ++j) {
      numf = fmaf(r[j], c1f[j], numf);
      denf = fmaf(c1f[j], c1f[j], denf);
    }
    double num = (double)redsum16f(numf) * k;
    double den = (double)redsum16f(denf) + EPSD;
    double gamma1 = num / den;            // div #3

    // pass 2
    double invd2 = 1.0 / (gamma1 + EPSD); // div #4
    double kd2 = k * invd2;
    float  A2f = (float)(kd2 * scale);
    float c2f[8];
    #pragma unroll
    for (int j = 0; j < 8; ++j) c2f[j] = qcent(r[j], A2f, kd2);

    // reconstruct + inverse rotation in f32 (linear path)
    double gamma = spiky ? rms : gamma1;
    float g2f = (float)(gamma * FSCD);
    float y[8];
    #pragma unroll
    for (int j = 0; j < 8; ++j) y[j] = (spiky ? c1f[j] : c2f[j]) * g2f;
    fwht128f_8(y, sAf, sBf, sCf, sDf);

    const float nf = (float)norms;
    float4 oa, ob;
    oa.x = y[0] * sga.x * nf;  oa.y = y[1] * sga.y * nf;
    oa.z = y[2] * sga.z * nf;  oa.w = y[3] * sga.w * nf;
    ob.x = y[4] * sgb.x * nf;  ob.y = y[5] * sgb.y * nf;
    ob.z = y[6] * sgb.z * nf;  ob.w = y[7] * sgb.w * nf;
    float* op = out + (4 * t + rw) * 128 + 8 * li;
    *reinterpret_cast<float4*>(op)     = oa;
    *reinterpret_cast<float4*>(op + 4) = ob;

    if (!more) break;
    t = tn; xa = na; xb = nb;
  }
}

extern "C" void kernel_launch(void* const* d_in, const int* in_sizes, int n_in,
                              void* d_out, int out_size, void* d_ws, size_t ws_size,
                              hipStream_t stream) {
  const float* x     = (const float*)d_in[0];
  const float* signs = (const float*)d_in[1];
  // d_in[2] = wht (unused: Sylvester Hadamard applied as in-register FWHT)
  const float* bnd   = (const float*)d_in[3];
  const float* ctr   = (const float*)d_in[4];
  float* out = (float*)d_out;

  int nrows  = out_size / 128;
  int nquads = nrows / 4;                    // 4 rows per wave
  int blocks = (nquads + 3) / 4;             // 4 waves per block
  if (blocks > 2048) blocks = 2048;
  hipLaunchKernelGGL(tq_kernel, dim3(blocks), dim3(256), 0, stream,
                     x, signs, bnd, ctr, out, nquads);
}

// Round 10
// 40.741 us; speedup vs baseline: 2.8693x; 1.0658x over previous
//
#include <hip/hip_runtime.h>

#define NCELL 512
#define EPSD  1e-8
#define EPSF  1e-8f
#define FSCD  0.08838834764831845    // 128**-0.5 (exact double of python repr)

// ---------------- lane-permute primitives (all within 16-lane DPP rows) -----
template<int CTRL>
__device__ __forceinline__ int idpp(int x){
  return __builtin_amdgcn_update_dpp(x, x, CTRL, 0xF, 0xF, false);
}
template<int CTRL>
__device__ __forceinline__ float fdpp(float x){
  return __int_as_float(idpp<CTRL>(__float_as_int(x)));
}
// f32 lane-xor within 16-lane rows
__device__ __forceinline__ float xorl1(float v){ return fdpp<0xB1>(v); }              // quad_perm [1,0,3,2]
__device__ __forceinline__ float xorl2(float v){ return fdpp<0x4E>(v); }              // quad_perm [2,3,0,1]
__device__ __forceinline__ float xorl4(float v){ return fdpp<0x1B>(fdpp<0x141>(v)); } // half_mirror(x^7) o quad[3,2,1,0](x^3)
__device__ __forceinline__ float xorl8(float v){ return fdpp<0x128>(v); }             // row_ror:8 == x^8 in 16

// f32 butterfly reductions over a 16-lane row; bitwise lane-uniform.
// (pure xor-DPP butterflies; no permlane16_swap anywhere)
__device__ __forceinline__ float redsum16f(float v){
  v += xorl1(v); v += xorl2(v); v += xorl4(v); v += xorl8(v); return v;
}
__device__ __forceinline__ float redmax16f(float v){
  v = fmaxf(v,xorl1(v)); v = fmaxf(v,xorl2(v));
  v = fmaxf(v,xorl4(v)); v = fmaxf(v,xorl8(v)); return v;
}

// ------- 128-pt FWHT, f32, 8 elems/lane (e = 8*li + j), 16 lanes/row --------
__device__ __forceinline__ void fwht128f_8(float r[8], float sA, float sB,
                                           float sC, float sD){
  float t;
  t=r[0]; r[0]=t+r[1]; r[1]=t-r[1];  t=r[2]; r[2]=t+r[3]; r[3]=t-r[3];
  t=r[4]; r[4]=t+r[5]; r[5]=t-r[5];  t=r[6]; r[6]=t+r[7]; r[7]=t-r[7];
  t=r[0]; r[0]=t+r[2]; r[2]=t-r[2];  t=r[1]; r[1]=t+r[3]; r[3]=t-r[3];
  t=r[4]; r[4]=t+r[6]; r[6]=t-r[6];  t=r[5]; r[5]=t+r[7]; r[7]=t-r[7];
  t=r[0]; r[0]=t+r[4]; r[4]=t-r[4];  t=r[1]; r[1]=t+r[5]; r[5]=t-r[5];
  t=r[2]; r[2]=t+r[6]; r[6]=t-r[6];  t=r[3]; r[3]=t+r[7]; r[7]=t-r[7];
  #pragma unroll
  for (int j=0;j<8;++j){ float o=xorl1(r[j]); r[j]=fmaf(sA, r[j], o); }
  #pragma unroll
  for (int j=0;j<8;++j){ float o=xorl2(r[j]); r[j]=fmaf(sB, r[j], o); }
  #pragma unroll
  for (int j=0;j<8;++j){ float o=xorl4(r[j]); r[j]=fmaf(sC, r[j], o); }
  #pragma unroll
  for (int j=0;j<8;++j){ float o=xorl8(r[j]); r[j]=fmaf(sD, r[j], o); }
}

__global__ __launch_bounds__(256) void tq_kernel(
    const float* __restrict__ x, const float* __restrict__ signs,
    const float* __restrict__ bnd, const float* __restrict__ ctr,
    float* __restrict__ out, int nquads)
{
  // One-gather searchsorted LUT (R8 reach construction, f32 payload):
  //   cell reach holds at most ONE boundary b*; entry {f32 b*, C_lo, C_hi}
  //   centroid = (b* < v) ? C_hi : C_lo  with v = r*kd in f32.
  //   f32 compare slop (~1e-7 rel) flips only boundary-adjacent buckets,
  //   each costing <=3e-3 in the output (vs 0.109 threshold).
  __shared__ float4 lutE[NCELL];   // 8 KB  {b*, C[n_lo], C[n_lo+1], 0}
  __shared__ double Bd[256];       // 2 KB  (255 boundaries + +inf sentinel)
  const int tid = threadIdx.x;
  if (tid < 255)  Bd[tid] = (double)bnd[tid];
  if (tid == 255) Bd[255] = __builtin_inf();
  __syncthreads();

  const double lo    = Bd[0] - 0.01;
  const double cw    = (Bd[254] + 0.01 - lo) * (1.0 / NCELL);
  const double scale = 1.0 / cw;
  const double nls   = -lo * scale;
  const double epsg  = cw * 1e-3;       // >> f32 addressing slop (~2e-4 cells)

  for (int c = tid; c < NCELL; c += 256) {
    double wl = (c == 0)         ? -__builtin_inf() : fma((double)c,     cw, lo) - epsg;
    double wr = (c == NCELL - 1) ?  __builtin_inf() : fma((double)(c+1), cw, lo) + epsg;
    int n = 0;
    #pragma unroll
    for (int s = 128; s; s >>= 1) n += (Bd[n + s - 1] < wl) ? s : 0;  // n = #{B < wl}
    double b  = Bd[n];                  // +inf sentinel at n==255
    bool  has = (b < wr);               // unique boundary in reach, if any
    float4 e;
    e.x = has ? (float)b : __builtin_inff();
    e.y = ctr[n];
    e.z = ctr[has ? (n + 1) : n];       // has => n<=254
    e.w = 0.f;
    lutE[c] = e;
  }
  __syncthreads();

  const int l   = tid & 63;
  const int li  = l & 15;         // lane within 16-lane row
  const int rw  = (l >> 4) & 3;   // row within wave (4 rows/wave)
  const int wid = tid >> 6;
  const float sAf = (l & 1) ? -1.f : 1.f;
  const float sBf = (l & 2) ? -1.f : 1.f;
  const float sCf = (l & 4) ? -1.f : 1.f;
  const float sDf = (l & 8) ? -1.f : 1.f;
  const double inv_maxc = 1.0 / (double)ctr[255];
  const float  scf   = (float)scale;
  const float  nlsf  = (float)nls;
  const float  icmax = (float)(NCELL - 1);
  const float  fscf  = (float)FSCD;

  const float4 sga = *reinterpret_cast<const float4*>(signs + 8 * li);
  const float4 sgb = *reinterpret_cast<const float4*>(signs + 8 * li + 4);

  // centroid C[searchsorted(B, vf)]: vf reused for cell addr; one gather,
  // one f32 compare
  auto qcent = [&](float vf) -> float {
    float cf = fmaf(vf, scf, nlsf);
    cf = fminf(fmaxf(cf, 0.0f), icmax);
    int ic = (int)cf;
    float4 e = lutE[ic];
    return (e.x < vf) ? e.z : e.y;
  };

  const int stride = gridDim.x * 4;
  int t = blockIdx.x * 4 + wid;
  if (t >= nquads) return;

  // software pipeline: prefetch next iteration's x while computing current
  const float* xp = x + (4 * t + rw) * 128 + 8 * li;
  float4 xa = *reinterpret_cast<const float4*>(xp);
  float4 xb = *reinterpret_cast<const float4*>(xp + 4);

  while (true) {
    const int tn = t + stride;
    const bool more = (tn < nquads);
    const int tpf = more ? tn : t;
    const float* np_ = x + (4 * tpf + rw) * 128 + 8 * li;
    float4 na = *reinterpret_cast<const float4*>(np_);
    float4 nb = *reinterpret_cast<const float4*>(np_ + 4);

    // sign fold exact in f32; r = unnormalized f32 FWHT(x*s)
    float r[8];
    r[0] = xa.x * sga.x;  r[1] = xa.y * sga.y;
    r[2] = xa.z * sga.z;  r[3] = xa.w * sga.w;
    r[4] = xb.x * sgb.x;  r[5] = xb.y * sgb.y;
    r[6] = xb.z * sgb.z;  r[7] = xb.w * sgb.w;

    // norms (f64 tail kept: feeds the sensitive is_spiky chain)
    float ssf = r[0] * r[0];
    #pragma unroll
    for (int j = 1; j < 8; ++j) ssf = fmaf(r[j], r[j], ssf);
    double norms = sqrt((double)redsum16f(ssf)) + EPSD;

    fwht128f_8(r, sAf, sBf, sCf, sDf);
    const double k  = FSCD / norms;       // only f64 div (per row)
    const float  kf = (float)k;

    // stats: f32 max/sum reductions (exact selection / 5e-7 err), f64 compare
    float mxf = fabsf(r[0]), asf = mxf;
    #pragma unroll
    for (int j = 1; j < 8; ++j) {
      float a = fabsf(r[j]); mxf = fmaxf(mxf, a); asf += a;
    }
    double xmax  = (double)redmax16f(mxf) * k;
    double xmean = fma((double)redsum16f(asf) * 0.0078125, k, EPSD);
    bool   spiky = xmax > 5.0 * xmean;
    float  rmsf  = (float)(xmax * inv_maxc);

    // pass 1: v = r*(k/(rms+EPS)), all f32 (flip cost <=3e-3, harmless)
    float invd1 = __builtin_amdgcn_rcpf(rmsf + EPSF);
    float kd1f = kf * invd1;
    float c1f[8];
    #pragma unroll
    for (int j = 0; j < 8; ++j) c1f[j] = qcent(r[j] * kd1f);

    // gamma refine in f32
    float numf = 0.f, denf = 0.f;
    #pragma unroll
    for (int j = 0; j < 8; ++j) {
      numf = fmaf(r[j], c1f[j], numf);
      denf = fmaf(c1f[j], c1f[j], denf);
    }
    float gamma1 = redsum16f(numf) * kf *
                   __builtin_amdgcn_rcpf(redsum16f(denf) + EPSF);

    // pass 2
    float invd2 = __builtin_amdgcn_rcpf(gamma1 + EPSF);
    float kd2f = kf * invd2;
    float c2f[8];
    #pragma unroll
    for (int j = 0; j < 8; ++j) c2f[j] = qcent(r[j] * kd2f);

    // reconstruct + inverse rotation in f32
    float gammaf = spiky ? rmsf : gamma1;
    float g2f = gammaf * fscf;
    float y[8];
    #pragma unroll
    for (int j = 0; j < 8; ++j) y[j] = (spiky ? c1f[j] : c2f[j]) * g2f;
    fwht128f_8(y, sAf, sBf, sCf, sDf);

    const float nf = (float)norms;
    float4 oa, ob;
    oa.x = y[0] * sga.x * nf;  oa.y = y[1] * sga.y * nf;
    oa.z = y[2] * sga.z * nf;  oa.w = y[3] * sga.w * nf;
    ob.x = y[4] * sgb.x * nf;  ob.y = y[5] * sgb.y * nf;
    ob.z = y[6] * sgb.z * nf;  ob.w = y[7] * sgb.w * nf;
    float* op = out + (4 * t + rw) * 128 + 8 * li;
    *reinterpret_cast<float4*>(op)     = oa;
    *reinterpret_cast<float4*>(op + 4) = ob;

    if (!more) break;
    t = tn; xa = na; xb = nb;
  }
}

extern "C" void kernel_launch(void* const* d_in, const int* in_sizes, int n_in,
                              void* d_out, int out_size, void* d_ws, size_t ws_size,
                              hipStream_t stream) {
  const float* x     = (const float*)d_in[0];
  const float* signs = (const float*)d_in[1];
  // d_in[2] = wht (unused: Sylvester Hadamard applied as in-register FWHT)
  const float* bnd   = (const float*)d_in[3];
  const float* ctr   = (const float*)d_in[4];
  float* out = (float*)d_out;

  int nrows  = out_size / 128;
  int nquads = nrows / 4;                    // 4 rows per wave
  int blocks = (nquads + 3) / 4;             // 4 waves per block
  if (blocks > 2048) blocks = 2048;
  hipLaunchKernelGGL(tq_kernel, dim3(blocks), dim3(256), 0, stream,
                     x, signs, bnd, ctr, out, nquads);
}

// Round 11
// 39.369 us; speedup vs baseline: 2.9693x; 1.0348x over previous
//
#include <hip/hip_runtime.h>

#define NCELL 512
#define EPSF  1e-8f
#define FSCD  0.08838834764831845    // 128**-0.5 (exact double of python repr)

// ---------------- lane-permute primitives (all within 16-lane DPP rows) -----
template<int CTRL>
__device__ __forceinline__ int idpp(int x){
  return __builtin_amdgcn_update_dpp(x, x, CTRL, 0xF, 0xF, false);
}
template<int CTRL>
__device__ __forceinline__ float fdpp(float x){
  return __int_as_float(idpp<CTRL>(__float_as_int(x)));
}
// f32 lane-xor within 16-lane rows
__device__ __forceinline__ float xorl1(float v){ return fdpp<0xB1>(v); }              // quad_perm [1,0,3,2]
__device__ __forceinline__ float xorl2(float v){ return fdpp<0x4E>(v); }              // quad_perm [2,3,0,1]
__device__ __forceinline__ float xorl4(float v){ return fdpp<0x1B>(fdpp<0x141>(v)); } // half_mirror(x^7) o quad[3,2,1,0](x^3)
__device__ __forceinline__ float xorl8(float v){ return fdpp<0x128>(v); }             // row_ror:8 == x^8 in 16

// f32 butterfly reductions over a 16-lane row; bitwise lane-uniform.
// (pure xor-DPP butterflies; no permlane16_swap anywhere)
__device__ __forceinline__ float redsum16f(float v){
  v += xorl1(v); v += xorl2(v); v += xorl4(v); v += xorl8(v); return v;
}
__device__ __forceinline__ float redmax16f(float v){
  v = fmaxf(v,xorl1(v)); v = fmaxf(v,xorl2(v));
  v = fmaxf(v,xorl4(v)); v = fmaxf(v,xorl8(v)); return v;
}

// ------- 128-pt FWHT, f32, 8 elems/lane (e = 8*li + j), 16 lanes/row --------
__device__ __forceinline__ void fwht128f_8(float r[8], float sA, float sB,
                                           float sC, float sD){
  float t;
  t=r[0]; r[0]=t+r[1]; r[1]=t-r[1];  t=r[2]; r[2]=t+r[3]; r[3]=t-r[3];
  t=r[4]; r[4]=t+r[5]; r[5]=t-r[5];  t=r[6]; r[6]=t+r[7]; r[7]=t-r[7];
  t=r[0]; r[0]=t+r[2]; r[2]=t-r[2];  t=r[1]; r[1]=t+r[3]; r[3]=t-r[3];
  t=r[4]; r[4]=t+r[6]; r[6]=t-r[6];  t=r[5]; r[5]=t+r[7]; r[7]=t-r[7];
  t=r[0]; r[0]=t+r[4]; r[4]=t-r[4];  t=r[1]; r[1]=t+r[5]; r[5]=t-r[5];
  t=r[2]; r[2]=t+r[6]; r[6]=t-r[6];  t=r[3]; r[3]=t+r[7]; r[7]=t-r[7];
  #pragma unroll
  for (int j=0;j<8;++j){ float o=xorl1(r[j]); r[j]=fmaf(sA, r[j], o); }
  #pragma unroll
  for (int j=0;j<8;++j){ float o=xorl2(r[j]); r[j]=fmaf(sB, r[j], o); }
  #pragma unroll
  for (int j=0;j<8;++j){ float o=xorl4(r[j]); r[j]=fmaf(sC, r[j], o); }
  #pragma unroll
  for (int j=0;j<8;++j){ float o=xorl8(r[j]); r[j]=fmaf(sD, r[j], o); }
}

__global__ __launch_bounds__(256) void tq_kernel(
    const float* __restrict__ x, const float* __restrict__ signs,
    const float* __restrict__ bnd, const float* __restrict__ ctr,
    float* __restrict__ out, int nquads)
{
  // One-gather searchsorted LUT (R8 reach construction, f32 payload):
  //   cell reach holds at most ONE boundary b*; entry {f32 b*, C_lo, C_hi}
  //   centroid = (b* < v) ? C_hi : C_lo  with v = r*kd in f32.
  //   f32 compare slop (~1e-7 rel) flips only boundary-adjacent buckets,
  //   each costing <=3e-3 in the output (vs 0.109 threshold).
  __shared__ float4 lutE[NCELL];   // 8 KB  {b*, C[n_lo], C[n_lo+1], 0}
  __shared__ double Bd[256];       // 2 KB  (255 boundaries + +inf sentinel)
  const int tid = threadIdx.x;
  if (tid < 255)  Bd[tid] = (double)bnd[tid];
  if (tid == 255) Bd[255] = __builtin_inf();
  __syncthreads();

  const double lo    = Bd[0] - 0.01;
  const double cw    = (Bd[254] + 0.01 - lo) * (1.0 / NCELL);
  const double scale = 1.0 / cw;
  const double nls   = -lo * scale;
  const double epsg  = cw * 1e-3;       // >> f32 addressing slop (~2e-4 cells)

  for (int c = tid; c < NCELL; c += 256) {
    double wl = (c == 0)         ? -__builtin_inf() : fma((double)c,     cw, lo) - epsg;
    double wr = (c == NCELL - 1) ?  __builtin_inf() : fma((double)(c+1), cw, lo) + epsg;
    int n = 0;
    #pragma unroll
    for (int s = 128; s; s >>= 1) n += (Bd[n + s - 1] < wl) ? s : 0;  // n = #{B < wl}
    double b  = Bd[n];                  // +inf sentinel at n==255
    bool  has = (b < wr);               // unique boundary in reach, if any
    float4 e;
    e.x = has ? (float)b : __builtin_inff();
    e.y = ctr[n];
    e.z = ctr[has ? (n + 1) : n];       // has => n<=254
    e.w = 0.f;
    lutE[c] = e;
  }
  __syncthreads();

  const int l   = tid & 63;
  const int li  = l & 15;         // lane within 16-lane row
  const int rw  = (l >> 4) & 3;   // row within wave (4 rows/wave)
  const int wid = tid >> 6;
  const float sAf = (l & 1) ? -1.f : 1.f;
  const float sBf = (l & 2) ? -1.f : 1.f;
  const float sCf = (l & 4) ? -1.f : 1.f;
  const float sDf = (l & 8) ? -1.f : 1.f;
  const float inv_maxcf = (float)(1.0 / (double)ctr[255]);
  const float scf   = (float)scale;
  const float nlsf  = (float)nls;
  const float icmax = (float)(NCELL - 1);
  const float fscf  = (float)FSCD;

  const float4 sga = *reinterpret_cast<const float4*>(signs + 8 * li);
  const float4 sgb = *reinterpret_cast<const float4*>(signs + 8 * li + 4);

  // centroid C[searchsorted(B, vf)]: vf reused for cell addr; one gather,
  // one f32 compare
  auto qcent = [&](float vf) -> float {
    float cf = fmaf(vf, scf, nlsf);
    cf = fminf(fmaxf(cf, 0.0f), icmax);
    int ic = (int)cf;
    float4 e = lutE[ic];
    return (e.x < vf) ? e.z : e.y;
  };

  const int stride = gridDim.x * 4;
  int t = blockIdx.x * 4 + wid;
  if (t >= nquads) return;

  // software pipeline: prefetch next iteration's x while computing current
  const float* xp = x + (4 * t + rw) * 128 + 8 * li;
  float4 xa = *reinterpret_cast<const float4*>(xp);
  float4 xb = *reinterpret_cast<const float4*>(xp + 4);

  while (true) {
    const int tn = t + stride;
    const bool more = (tn < nquads);
    const int tpf = more ? tn : t;
    const float* np_ = x + (4 * tpf + rw) * 128 + 8 * li;
    float4 na = *reinterpret_cast<const float4*>(np_);
    float4 nb = *reinterpret_cast<const float4*>(np_ + 4);

    // sign fold exact in f32; r = unnormalized f32 FWHT(x*s)
    float r[8];
    r[0] = xa.x * sga.x;  r[1] = xa.y * sga.y;
    r[2] = xa.z * sga.z;  r[3] = xa.w * sga.w;
    r[4] = xb.x * sgb.x;  r[5] = xb.y * sgb.y;
    r[6] = xb.z * sgb.z;  r[7] = xb.w * sgb.w;

    // norms = ||x||_2 + EPS, all f32 (uniform factor; spiky ratio is
    // k-scale-invariant to first order, so f32 noise here is harmless)
    float ssf = r[0] * r[0];
    #pragma unroll
    for (int j = 1; j < 8; ++j) ssf = fmaf(r[j], r[j], ssf);
    float nf = __builtin_amdgcn_sqrtf(redsum16f(ssf)) + EPSF;
    float kf = fscf * __builtin_amdgcn_rcpf(nf);

    fwht128f_8(r, sAf, sBf, sCf, sDf);

    // stats: f32 max is exact selection; |sum| err ~5e-7; spiky window ~1e-6
    float mxf = fabsf(r[0]), asf = mxf;
    #pragma unroll
    for (int j = 1; j < 8; ++j) {
      float a = fabsf(r[j]); mxf = fmaxf(mxf, a); asf += a;
    }
    float xmaxf  = redmax16f(mxf) * kf;
    float xmeanf = fmaf(redsum16f(asf) * 0.0078125f, kf, EPSF);
    bool  spiky  = xmaxf > 5.0f * xmeanf;
    float rmsf   = xmaxf * inv_maxcf;

    // pass 1: v = r*(k/(rms+EPS))
    float invd1 = __builtin_amdgcn_rcpf(rmsf + EPSF);
    float kd1f = kf * invd1;
    float c1f[8];
    #pragma unroll
    for (int j = 0; j < 8; ++j) c1f[j] = qcent(r[j] * kd1f);

    // gamma refine in f32
    float numf = 0.f, denf = 0.f;
    #pragma unroll
    for (int j = 0; j < 8; ++j) {
      numf = fmaf(r[j], c1f[j], numf);
      denf = fmaf(c1f[j], c1f[j], denf);
    }
    float gamma1 = redsum16f(numf) * kf *
                   __builtin_amdgcn_rcpf(redsum16f(denf) + EPSF);

    // pass 2
    float invd2 = __builtin_amdgcn_rcpf(gamma1 + EPSF);
    float kd2f = kf * invd2;
    float c2f[8];
    #pragma unroll
    for (int j = 0; j < 8; ++j) c2f[j] = qcent(r[j] * kd2f);

    // reconstruct + inverse rotation in f32
    float gammaf = spiky ? rmsf : gamma1;
    float g2f = gammaf * fscf;
    float y[8];
    #pragma unroll
    for (int j = 0; j < 8; ++j) y[j] = (spiky ? c1f[j] : c2f[j]) * g2f;
    fwht128f_8(y, sAf, sBf, sCf, sDf);

    float4 oa, ob;
    oa.x = y[0] * sga.x * nf;  oa.y = y[1] * sga.y * nf;
    oa.z = y[2] * sga.z * nf;  oa.w = y[3] * sga.w * nf;
    ob.x = y[4] * sgb.x * nf;  ob.y = y[5] * sgb.y * nf;
    ob.z = y[6] * sgb.z * nf;  ob.w = y[7] * sgb.w * nf;
    float* op = out + (4 * t + rw) * 128 + 8 * li;
    *reinterpret_cast<float4*>(op)     = oa;
    *reinterpret_cast<float4*>(op + 4) = ob;

    if (!more) break;
    t = tn; xa = na; xb = nb;
  }
}

extern "C" void kernel_launch(void* const* d_in, const int* in_sizes, int n_in,
                              void* d_out, int out_size, void* d_ws, size_t ws_size,
                              hipStream_t stream) {
  const float* x     = (const float*)d_in[0];
  const float* signs = (const float*)d_in[1];
  // d_in[2] = wht (unused: Sylvester Hadamard applied as in-register FWHT)
  const float* bnd   = (const float*)d_in[3];
  const float* ctr   = (const float*)d_in[4];
  float* out = (float*)d_out;

  int nrows  = out_size / 128;
  int nquads = nrows / 4;                    // 4 rows per wave
  int blocks = (nquads + 3) / 4;             // 4 waves per block
  if (blocks > 2048) blocks = 2048;
  hipLaunchKernelGGL(tq_kernel, dim3(blocks), dim3(256), 0, stream,
                     x, signs, bnd, ctr, out, nquads);
}

// Round 12
// 39.227 us; speedup vs baseline: 2.9800x; 1.0036x over previous
//
#include <hip/hip_runtime.h>
#include <hip/hip_fp16.h>

#define NCELL 512
#define EPSF  1e-8f
#define FSCD  0.08838834764831845    // 128**-0.5 (exact double of python repr)

// ---------------- lane-permute primitives (all within 16-lane DPP rows) -----
template<int CTRL>
__device__ __forceinline__ int idpp(int x){
  return __builtin_amdgcn_update_dpp(x, x, CTRL, 0xF, 0xF, false);
}
template<int CTRL>
__device__ __forceinline__ float fdpp(float x){
  return __int_as_float(idpp<CTRL>(__float_as_int(x)));
}
// f32 lane-xor within 16-lane rows
__device__ __forceinline__ float xorl1(float v){ return fdpp<0xB1>(v); }              // quad_perm [1,0,3,2]
__device__ __forceinline__ float xorl2(float v){ return fdpp<0x4E>(v); }              // quad_perm [2,3,0,1]
__device__ __forceinline__ float xorl4(float v){ return fdpp<0x1B>(fdpp<0x141>(v)); } // half_mirror(x^7) o quad[3,2,1,0](x^3)
__device__ __forceinline__ float xorl8(float v){ return fdpp<0x128>(v); }             // row_ror:8 == x^8 in 16

// f32 butterfly reductions over a 16-lane row; bitwise lane-uniform.
__device__ __forceinline__ float redsum16f(float v){
  v += xorl1(v); v += xorl2(v); v += xorl4(v); v += xorl8(v); return v;
}
__device__ __forceinline__ float redmax16f(float v){
  v = fmaxf(v,xorl1(v)); v = fmaxf(v,xorl2(v));
  v = fmaxf(v,xorl4(v)); v = fmaxf(v,xorl8(v)); return v;
}

// ------- 128-pt FWHT, f32, 8 elems/lane (e = 8*li + j), 16 lanes/row --------
__device__ __forceinline__ void fwht128f_8(float r[8], float sA, float sB,
                                           float sC, float sD){
  float t;
  t=r[0]; r[0]=t+r[1]; r[1]=t-r[1];  t=r[2]; r[2]=t+r[3]; r[3]=t-r[3];
  t=r[4]; r[4]=t+r[5]; r[5]=t-r[5];  t=r[6]; r[6]=t+r[7]; r[7]=t-r[7];
  t=r[0]; r[0]=t+r[2]; r[2]=t-r[2];  t=r[1]; r[1]=t+r[3]; r[3]=t-r[3];
  t=r[4]; r[4]=t+r[6]; r[6]=t-r[6];  t=r[5]; r[5]=t+r[7]; r[7]=t-r[7];
  t=r[0]; r[0]=t+r[4]; r[4]=t-r[4];  t=r[1]; r[1]=t+r[5]; r[5]=t-r[5];
  t=r[2]; r[2]=t+r[6]; r[6]=t-r[6];  t=r[3]; r[3]=t+r[7]; r[7]=t-r[7];
  #pragma unroll
  for (int j=0;j<8;++j){ float o=xorl1(r[j]); r[j]=fmaf(sA, r[j], o); }
  #pragma unroll
  for (int j=0;j<8;++j){ float o=xorl2(r[j]); r[j]=fmaf(sB, r[j], o); }
  #pragma unroll
  for (int j=0;j<8;++j){ float o=xorl4(r[j]); r[j]=fmaf(sC, r[j], o); }
  #pragma unroll
  for (int j=0;j<8;++j){ float o=xorl8(r[j]); r[j]=fmaf(sD, r[j], o); }
}

__global__ __launch_bounds__(256) void tq_kernel(
    const float* __restrict__ x, const float* __restrict__ signs,
    const float* __restrict__ bnd, const float* __restrict__ ctr,
    float* __restrict__ out, int nquads)
{
  // One-gather searchsorted LUT (R8 reach construction), 8-BYTE entries:
  //   {f32 b*, u32 = f16(C_hi)<<16 | f16(C_lo)}
  //   centroid = cvt_f32_f16( (b* < v) ? hi16 : lo16 )
  // f16 centroid rel err 4.9e-4 -> per-element output err <=5.5e-3
  // (||c*gamma||_2 ~= 1, norms ~= 11.3); gamma1 shift ~4e-5 rel. Both
  // far under the 0.093 margin. b* compare stays f32 (decisions as R11).
  __shared__ uint2  lutE[NCELL];   // 4 KB
  __shared__ double Bd[256];       // 2 KB (255 boundaries + +inf sentinel)
  const int tid = threadIdx.x;
  if (tid < 255)  Bd[tid] = (double)bnd[tid];
  if (tid == 255) Bd[255] = __builtin_inf();
  __syncthreads();

  const double lo    = Bd[0] - 0.01;
  const double cw    = (Bd[254] + 0.01 - lo) * (1.0 / NCELL);
  const double scale = 1.0 / cw;
  const double nls   = -lo * scale;
  const double epsg  = cw * 1e-3;       // >> f32 addressing slop (~2e-4 cells)

  for (int c = tid; c < NCELL; c += 256) {
    double wl = (c == 0)         ? -__builtin_inf() : fma((double)c,     cw, lo) - epsg;
    double wr = (c == NCELL - 1) ?  __builtin_inf() : fma((double)(c+1), cw, lo) + epsg;
    int n = 0;
    #pragma unroll
    for (int s = 128; s; s >>= 1) n += (Bd[n + s - 1] < wl) ? s : 0;  // n = #{B < wl}
    double b  = Bd[n];                  // +inf sentinel at n==255
    bool  has = (b < wr);               // unique boundary in reach, if any
    float c_lo = ctr[n];
    float c_hi = ctr[has ? (n + 1) : n];          // has => n<=254
    uint2 e;
    e.x = __float_as_uint(has ? (float)b : __builtin_inff());
    e.y = ((unsigned)__half_as_ushort(__float2half_rn(c_hi)) << 16)
        |  (unsigned)__half_as_ushort(__float2half_rn(c_lo));
    lutE[c] = e;
  }
  __syncthreads();

  const int l   = tid & 63;
  const int li  = l & 15;         // lane within 16-lane row
  const int rw  = (l >> 4) & 3;   // row within wave (4 rows/wave)
  const int wid = tid >> 6;
  const float sAf = (l & 1) ? -1.f : 1.f;
  const float sBf = (l & 2) ? -1.f : 1.f;
  const float sCf = (l & 4) ? -1.f : 1.f;
  const float sDf = (l & 8) ? -1.f : 1.f;
  const float inv_maxcf = (float)(1.0 / (double)ctr[255]);
  const float scf   = (float)scale;
  const float nlsf  = (float)nls;
  const float icmax = (float)(NCELL - 1);
  const float fscf  = (float)FSCD;

  const float4 sga = *reinterpret_cast<const float4*>(signs + 8 * li);
  const float4 sgb = *reinterpret_cast<const float4*>(signs + 8 * li + 4);

  // centroid C[searchsorted(B, vf)]: one b64 gather, one f32 compare,
  // one f16->f32 convert
  auto qcent = [&](float vf) -> float {
    float cf = fmaf(vf, scf, nlsf);
    cf = fminf(fmaxf(cf, 0.0f), icmax);
    int ic = (int)cf;
    uint2 e = lutE[ic];
    unsigned h = (__uint_as_float(e.x) < vf) ? (e.y >> 16) : (e.y & 0xFFFFu);
    return __half2float(__ushort_as_half((unsigned short)h));
  };

  const int stride = gridDim.x * 4;
  int t = blockIdx.x * 4 + wid;
  if (t >= nquads) return;

  // software pipeline: prefetch next iteration's x while computing current
  const float* xp = x + (4 * t + rw) * 128 + 8 * li;
  float4 xa = *reinterpret_cast<const float4*>(xp);
  float4 xb = *reinterpret_cast<const float4*>(xp + 4);

  while (true) {
    const int tn = t + stride;
    const bool more = (tn < nquads);
    const int tpf = more ? tn : t;
    const float* np_ = x + (4 * tpf + rw) * 128 + 8 * li;
    float4 na = *reinterpret_cast<const float4*>(np_);
    float4 nb = *reinterpret_cast<const float4*>(np_ + 4);

    // sign fold exact in f32; r = unnormalized f32 FWHT(x*s)
    float r[8];
    r[0] = xa.x * sga.x;  r[1] = xa.y * sga.y;
    r[2] = xa.z * sga.z;  r[3] = xa.w * sga.w;
    r[4] = xb.x * sgb.x;  r[5] = xb.y * sgb.y;
    r[6] = xb.z * sgb.z;  r[7] = xb.w * sgb.w;

    fwht128f_8(r, sAf, sBf, sCf, sDf);

    // fused stats: Parseval gives ||x||^2 = (sum r^2)/128 ; max ; |sum|
    float ssf = r[0]*r[0];
    float mxf = fabsf(r[0]), asf = mxf;
    #pragma unroll
    for (int j = 1; j < 8; ++j) {
      ssf = fmaf(r[j], r[j], ssf);
      float a = fabsf(r[j]); mxf = fmaxf(mxf, a); asf += a;
    }
    // norms = sqrt(ssr)/sqrt(128) + EPS  (uniform factor; spiky ratio
    // k-scale-invariant to first order)
    float nf = __builtin_amdgcn_sqrtf(redsum16f(ssf)) * fscf + EPSF;
    float kf = fscf * __builtin_amdgcn_rcpf(nf);

    float xmaxf  = redmax16f(mxf) * kf;
    float xmeanf = fmaf(redsum16f(asf) * 0.0078125f, kf, EPSF);
    bool  spiky  = xmaxf > 5.0f * xmeanf;
    float rmsf   = xmaxf * inv_maxcf;

    // pass 1: v = r*(k/(rms+EPS))
    float invd1 = __builtin_amdgcn_rcpf(rmsf + EPSF);
    float kd1f = kf * invd1;
    float c1f[8];
    #pragma unroll
    for (int j = 0; j < 8; ++j) c1f[j] = qcent(r[j] * kd1f);

    // gamma refine in f32
    float numf = 0.f, denf = 0.f;
    #pragma unroll
    for (int j = 0; j < 8; ++j) {
      numf = fmaf(r[j], c1f[j], numf);
      denf = fmaf(c1f[j], c1f[j], denf);
    }
    float gamma1 = redsum16f(numf) * kf *
                   __builtin_amdgcn_rcpf(redsum16f(denf) + EPSF);

    // pass 2
    float invd2 = __builtin_amdgcn_rcpf(gamma1 + EPSF);
    float kd2f = kf * invd2;
    float c2f[8];
    #pragma unroll
    for (int j = 0; j < 8; ++j) c2f[j] = qcent(r[j] * kd2f);

    // reconstruct; fold gamma*FSC*norms into ONE pre-FWHT scalar (linearity)
    float gammaf = spiky ? rmsf : gamma1;
    float g2f = gammaf * fscf * nf;
    float y[8];
    #pragma unroll
    for (int j = 0; j < 8; ++j) y[j] = (spiky ? c1f[j] : c2f[j]) * g2f;
    fwht128f_8(y, sAf, sBf, sCf, sDf);

    float4 oa, ob;
    oa.x = y[0] * sga.x;  oa.y = y[1] * sga.y;
    oa.z = y[2] * sga.z;  oa.w = y[3] * sga.w;
    ob.x = y[4] * sgb.x;  ob.y = y[5] * sgb.y;
    ob.z = y[6] * sgb.z;  ob.w = y[7] * sgb.w;
    float* op = out + (4 * t + rw) * 128 + 8 * li;
    *reinterpret_cast<float4*>(op)     = oa;
    *reinterpret_cast<float4*>(op + 4) = ob;

    if (!more) break;
    t = tn; xa = na; xb = nb;
  }
}

extern "C" void kernel_launch(void* const* d_in, const int* in_sizes, int n_in,
                              void* d_out, int out_size, void* d_ws, size_t ws_size,
                              hipStream_t stream) {
  const float* x     = (const float*)d_in[0];
  const float* signs = (const float*)d_in[1];
  // d_in[2] = wht (unused: Sylvester Hadamard applied as in-register FWHT)
  const float* bnd   = (const float*)d_in[3];
  const float* ctr   = (const float*)d_in[4];
  float* out = (float*)d_out;

  int nrows  = out_size / 128;
  int nquads = nrows / 4;                    // 4 rows per wave
  int blocks = (nquads + 3) / 4;             // 4 waves per block
  if (blocks > 2048) blocks = 2048;
  hipLaunchKernelGGL(tq_kernel, dim3(blocks), dim3(256), 0, stream,
                     x, signs, bnd, ctr, out, nquads);
}